// Round 5
// baseline (622.472 us; speedup 1.0000x reference)
//
#include <hip/hip_runtime.h>

#define NN   51200
#define EE   819200
#define GG   256
#define NN2  102400
#define AA   204800
#define EE2  409600
#define DD   64
#define LL   5

typedef __attribute__((ext_vector_type(8))) short bf16x8;
typedef __attribute__((ext_vector_type(4))) float f32x4;
typedef unsigned short ushort_t;

// ---------------- workspace layout (bytes) ----------------
#define OFF_H      ((size_t)0)          // emb h; post-GIN: yrel spans OFF_H..OFF_H2
#define OFF_AGG    ((size_t)13107200)   // GIN: h ping-pong buffer B
#define OFF_H2     ((size_t)26214400)   // GIN: buffer A; layer-4 output = h2 (alive to kpoolg)
#define OFF_XP     ((size_t)39321600)   // front 4.9 MB: rank1/rank2 during CSR build; later xp
#define OFF_PERM   ((size_t)60293120)   // perm (200KB) inside xp region; dead before kgather2 writes xp
#define OFF_YROOT  ((size_t)65536000)   // prepped bf16 weights during GIN; yroot after
#define OFF_OFFS1  ((size_t)91750400)
#define OFF_COL1   ((size_t)91955216)
#define OFF_OFFS2  ((size_t)95232016)
#define OFF_COL2   ((size_t)95641632)
#define OFF_CNT1   ((size_t)97280032)   // zeroed region starts here
#define OFF_CUR1   ((size_t)97484832)   // pstat2[5][32][128] during GIN (zeroed by memset)
#define OFF_CNT2   ((size_t)97689632)
#define OFF_CUR2   ((size_t)98099232)
#define OFF_STATS  ((size_t)98508832)   // dbin[64], dstart[64], dcur[64] (zeroed)
#define ZERO_BYTES ((size_t)1231360)
#define OFF_ISO    ((size_t)98511392)
#define OFF_M      ((size_t)98920992)
#define WS_NEEDED  ((size_t)99052064)

__device__ __forceinline__ int waveInclScan(int v, int lane) {
#pragma unroll
    for (int off = 1; off < 64; off <<= 1) {
        int t = __shfl_up(v, off, 64);
        if (lane >= off) v += t;
    }
    return v;
}

// ---------------- split-bf16 helpers ----------------
__device__ __forceinline__ void bsplit(float x, ushort_t& hi, ushort_t& lo) {
    union { float f; unsigned u; } a; a.f = x;
    unsigned hb = (a.u + 0x7FFFu + ((a.u >> 16) & 1u)) >> 16;   // RNE to bf16
    union { unsigned u; float f; } h; h.u = hb << 16;
    float r = x - h.f;
    union { float f; unsigned u; } b; b.f = r;
    unsigned lb = (b.u + 0x7FFFu + ((b.u >> 16) & 1u)) >> 16;
    hi = (ushort_t)hb; lo = (ushort_t)lb;
}

// ---------------- CSR histogram + rank capture (R3 structure: 4 edges/thread, max streams) ----------------
__global__ void khist_m(const int* __restrict__ dst1, const int* __restrict__ dst2,
                        int* __restrict__ cnt1, int* __restrict__ cnt2,
                        int* __restrict__ rank1, int* __restrict__ rank2) {
    int b = blockIdx.x;
    if (b < 800) {
        int i = (b * 256 + threadIdx.x) * 4;
        int4 d = *(const int4*)(dst1 + i);
        int4 r;
        r.x = atomicAdd(&cnt1[d.x], 1);
        r.y = atomicAdd(&cnt1[d.y], 1);
        r.z = atomicAdd(&cnt1[d.z], 1);
        r.w = atomicAdd(&cnt1[d.w], 1);
        *(int4*)(rank1 + i) = r;
    } else {
        int i = ((b - 800) * 256 + threadIdx.x) * 4;
        int4 d = *(const int4*)(dst2 + i);
        int4 r;
        r.x = atomicAdd(&cnt2[d.x], 1);
        r.y = atomicAdd(&cnt2[d.y], 1);
        r.z = atomicAdd(&cnt2[d.z], 1);
        r.w = atomicAdd(&cnt2[d.w], 1);
        *(int4*)(rank2 + i) = r;
    }
}

// ---------------- prep: embedding + weight prep + iso argmax ----------------
__global__ void kprepx(const float* __restrict__ x, const float* __restrict__ embW,
                       const float* __restrict__ embB, float* __restrict__ h,
                       const float* __restrict__ gW1, const float* __restrict__ gW2,
                       ushort_t* __restrict__ w1h, ushort_t* __restrict__ w1l,
                       ushort_t* __restrict__ w2h, ushort_t* __restrict__ w2l,
                       const float* __restrict__ iso, int* __restrict__ isoIdx) {
    int b = blockIdx.x;
    if (b < 12800) {
        int t = b * 256 + threadIdx.x;
        int n = t >> 6, d = t & 63;
        float acc = embB[d];
        const float* xr = x + n * 40;
#pragma unroll
        for (int k = 0; k < 40; ++k) acc = fmaf(xr[k], embW[k * 64 + d], acc);
        h[(size_t)n * 64 + d] = fmaxf(acc, 0.f);
    } else if (b < 12840) {
        int t = (b - 12800) * 256 + threadIdx.x;
        int lane = t & 63, frag = t >> 6;
        int c15 = lane & 15, q = lane >> 4;
        if (frag < 80) {
            int kt = frag & 1, nt = (frag >> 1) & 7, l = frag >> 4;
            const float* W = gW1 + l * 8192;
            ushort_t* oh = w1h + ((size_t)frag * 64 + lane) * 8;
            ushort_t* ol = w1l + ((size_t)frag * 64 + lane) * 8;
            int kb = kt * 32 + q * 8, colw = nt * 16 + c15;
#pragma unroll
            for (int j = 0; j < 8; ++j) {
                ushort_t hi, lo; bsplit(W[(kb + j) * 128 + colw], hi, lo);
                oh[j] = hi; ol[j] = lo;
            }
        } else if (frag < 160) {
            int f = frag - 80;
            int kt = f & 3, nt = (f >> 2) & 3, l = f >> 4;
            const float* W = gW2 + l * 8192;
            ushort_t* oh = w2h + ((size_t)f * 64 + lane) * 8;
            ushort_t* ol = w2l + ((size_t)f * 64 + lane) * 8;
            int kb = kt * 32 + q * 8, colw = nt * 16 + c15;
#pragma unroll
            for (int j = 0; j < 8; ++j) {
                ushort_t hi, lo; bsplit(W[(kb + j) * 64 + colw], hi, lo);
                oh[j] = hi; ol[j] = lo;
            }
        }
    } else {
        int j = (b - 12840) * 256 + threadIdx.x;
        const float4* r4 = (const float4*)(iso + (size_t)j * 36);
        int best = 0;
#pragma unroll
        for (int k = 0; k < 9; ++k) {
            float4 v = r4[k];
            if (v.x > 0.5f) best = 4 * k;
            if (v.y > 0.5f) best = 4 * k + 1;
            if (v.z > 0.5f) best = 4 * k + 2;
            if (v.w > 0.5f) best = 4 * k + 3;
        }
        isoIdx[j] = best;
    }
}

__global__ void kreduce_m(const int* __restrict__ cnt1, const int* __restrict__ cnt2,
                          int* __restrict__ bsum1, int* __restrict__ bsum2) {
    __shared__ int wsr[4];
    int b = blockIdx.x;
    const int* cnt; int* bsum;
    if (b < 50) { cnt = cnt1; bsum = bsum1; }
    else { b -= 50; cnt = cnt2; bsum = bsum2; }
    int tid = threadIdx.x, lane = tid & 63, wid = tid >> 6;
    int4 v = ((const int4*)(cnt + (size_t)b * 1024))[tid];
    int s = v.x + v.y + v.z + v.w;
#pragma unroll
    for (int off = 32; off; off >>= 1) s += __shfl_down(s, off, 64);
    if (lane == 0) wsr[wid] = s;
    __syncthreads();
    if (tid == 0) bsum[b] = wsr[0] + wsr[1] + wsr[2] + wsr[3];
}

__global__ void kscan_small_m(const int* __restrict__ bsum1, const int* __restrict__ bsum2,
                              int* __restrict__ boffs1, int* __restrict__ boffs2) {
    __shared__ int w0s;
    const int* bsum = blockIdx.x ? bsum2 : bsum1;
    int* boffs = blockIdx.x ? boffs2 : boffs1;
    int nb = blockIdx.x ? 100 : 50;
    int tid = threadIdx.x, lane = tid & 63, wid = tid >> 6;
    int v = (tid < nb) ? bsum[tid] : 0;
    int incl = waveInclScan(v, lane);
    if (tid == 63) w0s = incl;
    __syncthreads();
    int excl = incl - v + (wid ? w0s : 0);
    if (tid < nb) boffs[tid] = excl;
}

// scan-apply; graph1 blocks also build the degree histogram for the counting sort
__global__ void kscan_apply_m(const int* __restrict__ cnt1, const int* __restrict__ cnt2,
                              const int* __restrict__ boffs1, const int* __restrict__ boffs2,
                              int* __restrict__ offs1, int* __restrict__ offs2,
                              int* __restrict__ dbin) {
    __shared__ int wsum[4];
    __shared__ int hbin[64];
    int b = blockIdx.x;
    const int* cnt; const int* boffs; int* offs; int n, total;
    bool g1 = (b < 50);
    if (g1) { cnt = cnt1; boffs = boffs1; offs = offs1; n = NN; total = EE; }
    else { b -= 50; cnt = cnt2; boffs = boffs2; offs = offs2; n = NN2; total = EE2; }
    int tid = threadIdx.x, lane = tid & 63, wid = tid >> 6;
    if (g1 && tid < 64) hbin[tid] = 0;
    size_t base = (size_t)b * 1024;
    int4 v = ((const int4*)(cnt + base))[tid];
    int s = v.x + v.y + v.z + v.w;
    int incl = waveInclScan(s, lane);
    if (lane == 63) wsum[wid] = incl;
    __syncthreads();
    if (g1) {
        atomicAdd(&hbin[v.x < 63 ? v.x : 63], 1);
        atomicAdd(&hbin[v.y < 63 ? v.y : 63], 1);
        atomicAdd(&hbin[v.z < 63 ? v.z : 63], 1);
        atomicAdd(&hbin[v.w < 63 ? v.w : 63], 1);
    }
    int woff = boffs[b];
#pragma unroll
    for (int w = 0; w < 3; ++w) woff += (w < wid) ? wsum[w] : 0;
    int excl = woff + incl - s;
    int4 o;
    o.x = excl; o.y = excl + v.x; o.z = o.y + v.y; o.w = o.z + v.z;
    ((int4*)(offs + base))[tid] = o;
    if (tid == 0 && b == 0) offs[n] = total;
    __syncthreads();
    if (g1 && tid < 64 && hbin[tid]) atomicAdd(&dbin[tid], hbin[tid]);
}

// DESCENDING placement base: bin 63 (heaviest) first -> heavy blocks scheduled first,
// light blocks backfill the kernel tail (fixes end-of-kernel occupancy hole).
__global__ void kdegscan(const int* __restrict__ dbin, int* __restrict__ dstart) {
    int tid = threadIdx.x;
    int v = dbin[tid];
    int incl = waveInclScan(v, tid);
    dstart[tid] = NN - incl;
}

// ---------------- fused: atomic-free CSR fill + degree-sort placement ----------------
// perm lives at OFF_PERM (NOT aliasing rank1), so place blocks can run concurrently
// with fill blocks that still read rank1/rank2.
__global__ __launch_bounds__(256) void kfill2(
        const int* __restrict__ src1, const int* __restrict__ dst1,
        const int* __restrict__ ea, const int* __restrict__ rank1,
        const int* __restrict__ offs1, int* __restrict__ col1,
        const int* __restrict__ src2, const int* __restrict__ dst2,
        const int* __restrict__ rank2, const int* __restrict__ offs2,
        int* __restrict__ col2,
        const int* __restrict__ dstart, int* __restrict__ dcur,
        int* __restrict__ perm) {
    int b = blockIdx.x;
    if (b < 800) {
        int i = (b * 256 + threadIdx.x) * 4;
        int4 d4 = *(const int4*)(dst1 + i);
        int4 s4 = *(const int4*)(src1 + i);
        int4 r4 = *(const int4*)(rank1 + i);
        int4 e0 = *(const int4*)(ea + 2 * i);
        int4 e1 = *(const int4*)(ea + 2 * i + 4);
        col1[offs1[d4.x] + r4.x] = s4.x | ((e0.x * 3 + e0.y) << 16);
        col1[offs1[d4.y] + r4.y] = s4.y | ((e0.z * 3 + e0.w) << 16);
        col1[offs1[d4.z] + r4.z] = s4.z | ((e1.x * 3 + e1.y) << 16);
        col1[offs1[d4.w] + r4.w] = s4.w | ((e1.z * 3 + e1.w) << 16);
    } else if (b < 1200) {
        int i = ((b - 800) * 256 + threadIdx.x) * 4;
        int4 d4 = *(const int4*)(dst2 + i);
        int4 s4 = *(const int4*)(src2 + i);
        int4 r4 = *(const int4*)(rank2 + i);
        col2[offs2[d4.x] + r4.x] = s4.x;
        col2[offs2[d4.y] + r4.y] = s4.y;
        col2[offs2[d4.z] + r4.z] = s4.z;
        col2[offs2[d4.w] + r4.w] = s4.w;
    } else {
        // two-level counting-sort placement: LDS-local ranks + one global atomic per (block,bin)
        __shared__ int lhist[64];
        __shared__ int lbase[64];
        int tid = threadIdx.x;
        if (tid < 64) lhist[tid] = 0;
        __syncthreads();
        int n = (b - 1200) * 256 + tid;
        int d = offs1[n + 1] - offs1[n]; d = d < 63 ? d : 63;
        int lr = atomicAdd(&lhist[d], 1);
        __syncthreads();
        if (tid < 64) {
            int c = lhist[tid];
            lbase[tid] = c ? atomicAdd(&dcur[tid], c) : 0;
        }
        __syncthreads();
        perm[dstart[d] + lbase[d] + lr] = n;
    }
}

// ---------------- per-node BN+ReLU transform, in place (once per node, not per edge) ----------------
__global__ __launch_bounds__(256) void ktrans(float* __restrict__ h,
                                              const float* __restrict__ pst,
                                              const float* __restrict__ gamma,
                                              const float* __restrict__ beta) {
    __shared__ float sstat[128];
    __shared__ float sSC[64], sSH[64];
    int tid = threadIdx.x;
    if (tid < 128) {
        float s = 0.f;
        const float* p = pst + tid;
#pragma unroll
        for (int i = 0; i < 32; ++i) s += p[i * 128];
        sstat[tid] = s;
    }
    __syncthreads();
    if (tid < 64) {
        float mu = sstat[tid] * (1.f / NN);
        float var = sstat[64 + tid] * (1.f / NN) - mu * mu;
        float sc = gamma[tid] * rsqrtf(var + 1e-5f);
        sSC[tid] = sc; sSH[tid] = beta[tid] - mu * sc;
    }
    __syncthreads();
    int c = (tid & 15) * 4;
    float4 sc4 = *(const float4*)(sSC + c);
    float4 sh4 = *(const float4*)(sSH + c);
    float4* hp = (float4*)h;
    size_t base = (size_t)blockIdx.x * 1024 + tid;
#pragma unroll
    for (int r = 0; r < 4; ++r) {
        float4 v = hp[base + r * 256];
        v.x = fmaxf(fmaf(v.x, sc4.x, sh4.x), 0.f);
        v.y = fmaxf(fmaf(v.y, sc4.y, sh4.y), 0.f);
        v.z = fmaxf(fmaf(v.z, sc4.z, sh4.z), 0.f);
        v.w = fmaxf(fmaf(v.w, sc4.w, sh4.w), 0.f);
        hp[base + r * 256] = v;
    }
}

// ---------------- fused GIN layer: gather(16 perm'd nodes) -> LDS -> MFMA MLP -> hout + stats ----
// Degree-sorted blocks => full chunks dominate; gather does unmasked full chunks + one masked tail.
__global__ __launch_bounds__(256) void kglayer(
    const float* __restrict__ hin, float* __restrict__ hout,
    const int* __restrict__ perm,
    const int* __restrict__ offs, const int* __restrict__ col,
    const float* __restrict__ e1, const float* __restrict__ e2,
    const ushort_t* __restrict__ w1h, const ushort_t* __restrict__ w1l,
    const ushort_t* __restrict__ w2h, const ushort_t* __restrict__ w2l,
    const float* __restrict__ b1, const float* __restrict__ b2,
    float* __restrict__ pstout) {
    __shared__ float etab[13 * 64];
    __shared__ int sPerm[16];
    __shared__ float sMLP[16 * 132];   // sA stride-68 aliases front; sH stride-132
    float* sA = sMLP;
    float* sH = sMLP;
    int tid = threadIdx.x;
    if (tid < 16) sPerm[tid] = perm[blockIdx.x * 16 + tid];
    for (int idx = tid; idx < 13 * 64; idx += 256) {
        int ci = idx >> 6, dd = idx & 63;
        etab[idx] = e1[(ci / 3) * 64 + dd] + e2[(ci % 3) * 64 + dd];
    }
    __syncthreads();
    int lane = tid & 63, wv = tid >> 6;
    int c15 = lane & 15, q = lane >> 4;

    // ---- gather node n into sA ----
    {
        int n = sPerm[wv * 4 + q];
        int s0 = offs[n], s1 = offs[n + 1];
        float4 sx = *(const float4*)(hin + (size_t)n * 64 + 4 * c15);
        float4 et = *(const float4*)(etab + 12 * 64 + 4 * c15);
        float a0 = sx.x + et.x, a1 = sx.y + et.y, a2 = sx.z + et.z, a3 = sx.w + et.w;
        int deg = s1 - s0;
        if (deg > 0) {
            const int* cp = col + s0;
            int nfull = deg >> 3, rem = deg & 7;
            int vv[8];
#pragma unroll
            for (int j = 0; j < 8; ++j) {
                int idx = j < deg ? j : deg - 1;
                vv[j] = cp[idx];
            }
            for (int it = 0; it < nfull; ++it) {
                float4 xv[8], tv[8];
#pragma unroll
                for (int j = 0; j < 8; ++j) {
                    xv[j] = *(const float4*)(hin + (size_t)(vv[j] & 0xFFFF) * 64 + 4 * c15);
                    tv[j] = *(const float4*)(etab + (vv[j] >> 16) * 64 + 4 * c15);
                }
                int e8 = (it + 1) * 8;
                bool more = e8 < deg;
                int nx[8];
                if (more) {
#pragma unroll
                    for (int j = 0; j < 8; ++j) {
                        int idx = e8 + j; idx = idx < deg ? idx : deg - 1;
                        nx[j] = cp[idx];
                    }
                }
#pragma unroll
                for (int j = 0; j < 8; ++j) {
                    a0 += xv[j].x + tv[j].x;
                    a1 += xv[j].y + tv[j].y;
                    a2 += xv[j].z + tv[j].z;
                    a3 += xv[j].w + tv[j].w;
                }
                if (more) {
#pragma unroll
                    for (int j = 0; j < 8; ++j) vv[j] = nx[j];
                }
            }
            if (rem) {
                float4 xv[8], tv[8];
#pragma unroll
                for (int j = 0; j < 8; ++j) {
                    xv[j] = *(const float4*)(hin + (size_t)(vv[j] & 0xFFFF) * 64 + 4 * c15);
                    tv[j] = *(const float4*)(etab + (vv[j] >> 16) * 64 + 4 * c15);
                }
#pragma unroll
                for (int j = 0; j < 8; ++j) {
                    float mm = (j < rem) ? 1.f : 0.f;
                    a0 = fmaf(xv[j].x + tv[j].x, mm, a0);
                    a1 = fmaf(xv[j].y + tv[j].y, mm, a1);
                    a2 = fmaf(xv[j].z + tv[j].z, mm, a2);
                    a3 = fmaf(xv[j].w + tv[j].w, mm, a3);
                }
            }
        }
        *(float4*)(sA + (wv * 4 + q) * 68 + 4 * c15) = make_float4(a0, a1, a2, a3);
    }
    __syncthreads();

    // ---- A-frags to regs (sA dies after next sync; sH aliases) ----
    bf16x8 ah[2], al[2];
#pragma unroll
    for (int kt = 0; kt < 2; ++kt) {
        const float* p = sA + c15 * 68 + kt * 32 + q * 8;
        float4 x0 = *(const float4*)p;
        float4 x1 = *(const float4*)(p + 4);
        float xs[8] = {x0.x, x0.y, x0.z, x0.w, x1.x, x1.y, x1.z, x1.w};
#pragma unroll
        for (int j = 0; j < 8; ++j) {
            ushort_t hi, lo; bsplit(xs[j], hi, lo);
            ah[kt][j] = (short)hi; al[kt][j] = (short)lo;
        }
    }
    __syncthreads();

    // ---- GEMM1: nt = 2wv+j ----
    f32x4 acc1[2];
#pragma unroll
    for (int j = 0; j < 2; ++j) { f32x4 z = {0.f, 0.f, 0.f, 0.f}; acc1[j] = z; }
#pragma unroll
    for (int kt = 0; kt < 2; ++kt) {
#pragma unroll
        for (int j = 0; j < 2; ++j) {
            int nt = 2 * wv + j;
            size_t fo = ((size_t)((nt * 2 + kt) * 64 + lane)) * 8;
            bf16x8 bh = *(const bf16x8*)(w1h + fo);
            bf16x8 bl = *(const bf16x8*)(w1l + fo);
            acc1[j] = __builtin_amdgcn_mfma_f32_16x16x32_bf16(ah[kt], bh, acc1[j], 0, 0, 0);
            acc1[j] = __builtin_amdgcn_mfma_f32_16x16x32_bf16(al[kt], bh, acc1[j], 0, 0, 0);
            acc1[j] = __builtin_amdgcn_mfma_f32_16x16x32_bf16(ah[kt], bl, acc1[j], 0, 0, 0);
        }
    }
#pragma unroll
    for (int j = 0; j < 2; ++j) {
        int nt = 2 * wv + j;
        float bias = b1[nt * 16 + c15];
#pragma unroll
        for (int rg = 0; rg < 4; ++rg)
            sH[(4 * q + rg) * 132 + nt * 16 + c15] = fmaxf(acc1[j][rg] + bias, 0.f);
    }
    __syncthreads();

    // ---- GEMM2: nt = wv ----
    f32x4 acc2 = {0.f, 0.f, 0.f, 0.f};
#pragma unroll
    for (int kt = 0; kt < 4; ++kt) {
        const float* p = sH + c15 * 132 + kt * 32 + q * 8;
        float4 x0 = *(const float4*)p;
        float4 x1 = *(const float4*)(p + 4);
        float xs[8] = {x0.x, x0.y, x0.z, x0.w, x1.x, x1.y, x1.z, x1.w};
        bf16x8 a2h, a2l;
#pragma unroll
        for (int j = 0; j < 8; ++j) {
            ushort_t hi, lo; bsplit(xs[j], hi, lo);
            a2h[j] = (short)hi; a2l[j] = (short)lo;
        }
        size_t fo = ((size_t)((wv * 4 + kt) * 64 + lane)) * 8;
        bf16x8 bh = *(const bf16x8*)(w2h + fo);
        bf16x8 bl = *(const bf16x8*)(w2l + fo);
        acc2 = __builtin_amdgcn_mfma_f32_16x16x32_bf16(a2h, bh, acc2, 0, 0, 0);
        acc2 = __builtin_amdgcn_mfma_f32_16x16x32_bf16(a2l, bh, acc2, 0, 0, 0);
        acc2 = __builtin_amdgcn_mfma_f32_16x16x32_bf16(a2h, bl, acc2, 0, 0, 0);
    }
    {
        float bias = b2[wv * 16 + c15];
        float s = 0.f, s2 = 0.f;
#pragma unroll
        for (int rg = 0; rg < 4; ++rg) {
            float v = acc2[rg] + bias;
            hout[(size_t)sPerm[4 * q + rg] * 64 + wv * 16 + c15] = v;
            s += v; s2 += v * v;
        }
        s += __shfl_xor(s, 16, 64);  s += __shfl_xor(s, 32, 64);
        s2 += __shfl_xor(s2, 16, 64); s2 += __shfl_xor(s2, 32, 64);
        if (q == 0) {
            float* ps = pstout + (size_t)(blockIdx.x & 31) * 128;
            atomicAdd(&ps[wv * 16 + c15], s);
            atomicAdd(&ps[64 + wv * 16 + c15], s2);
        }
    }
}

// ---------------- GraphConv GEMMs; FIRST fuses 2-set avg-pool + final-layer BN during staging + iso rows ----------------
template <int FIRST>
__global__ __launch_bounds__(256) void kgcmm(const float* __restrict__ X,
                                             const float* __restrict__ Wrel,
                                             const float* __restrict__ Wroot,
                                             const float* __restrict__ WrelIso,
                                             const float* __restrict__ WrootIso,
                                             const int* __restrict__ isoIdx,
                                             float* __restrict__ Yrel,
                                             float* __restrict__ Yroot,
                                             const float* __restrict__ pst,
                                             const float* __restrict__ g4,
                                             const float* __restrict__ b4,
                                             const int* __restrict__ a0g,
                                             const float* __restrict__ h2src) {
    __shared__ float sX[64 * 65];
    __shared__ float sR[64 * 64];
    __shared__ float sT[64 * 64];
    __shared__ float sstat[128];
    __shared__ float sSC[64], sSH[64];
    int tid = threadIdx.x, blk = blockIdx.x;
    if (FIRST && tid < 128) {
        float s = 0.f;
        const float* p = pst + tid;
#pragma unroll
        for (int i = 0; i < 32; ++i) s += p[i * 128];
        sstat[tid] = s;
    }
#pragma unroll
    for (int i = tid; i < 1024; i += 256) {
        ((float4*)sR)[i] = ((const float4*)Wrel)[i];
        ((float4*)sT)[i] = ((const float4*)Wroot)[i];
    }
    __syncthreads();
    if (FIRST && tid < 64) {
        float mu = sstat[tid] * (1.f / NN);
        float var = sstat[64 + tid] * (1.f / NN) - mu * mu;
        float sc = g4[tid] * rsqrtf(var + 1e-5f);
        sSC[tid] = sc;
        sSH[tid] = b4[tid] - mu * sc;
    }
    __syncthreads();
#pragma unroll
    for (int i = tid; i < 1024; i += 256) {
        int row = i >> 4, c = (i & 15) << 2;
        float4 v;
        if (FIRST) {
            int grow = blk * 64 + row;
            int na = a0g[2 * grow], nb = a0g[2 * grow + 1];
            float4 va = *(const float4*)(h2src + (size_t)na * 64 + c);
            float4 vb = *(const float4*)(h2src + (size_t)nb * 64 + c);
            v.x = 0.5f * (va.x + vb.x); v.y = 0.5f * (va.y + vb.y);
            v.z = 0.5f * (va.z + vb.z); v.w = 0.5f * (va.w + vb.w);
            v.x = fmaf(v.x, sSC[c], sSH[c]);
            v.y = fmaf(v.y, sSC[c + 1], sSH[c + 1]);
            v.z = fmaf(v.z, sSC[c + 2], sSH[c + 2]);
            v.w = fmaf(v.w, sSC[c + 3], sSH[c + 3]);
        } else {
            v = ((const float4*)(X + (size_t)blk * 4096))[i];
        }
        float* p = sX + row * 65 + c;
        p[0] = v.x; p[1] = v.y; p[2] = v.z; p[3] = v.w;
    }
    __syncthreads();
    int tm = tid >> 4, tn = tid & 15;
    float aR[4][4], aT[4][4];
#pragma unroll
    for (int r = 0; r < 4; ++r)
#pragma unroll
        for (int c = 0; c < 4; ++c) { aR[r][c] = 0.f; aT[r][c] = 0.f; }
    const float* xrow = sX + tm * 4 * 65;
#pragma unroll 4
    for (int k = 0; k < 64; ++k) {
        float a0 = xrow[k], a1 = xrow[65 + k], a2 = xrow[130 + k], a3 = xrow[195 + k];
        float4 br = *(const float4*)(sR + k * 64 + tn * 4);
        float4 bt = *(const float4*)(sT + k * 64 + tn * 4);
        float rb[4] = {br.x, br.y, br.z, br.w};
        float tb[4] = {bt.x, bt.y, bt.z, bt.w};
#pragma unroll
        for (int c = 0; c < 4; ++c) {
            aR[0][c] = fmaf(a0, rb[c], aR[0][c]); aR[1][c] = fmaf(a1, rb[c], aR[1][c]);
            aR[2][c] = fmaf(a2, rb[c], aR[2][c]); aR[3][c] = fmaf(a3, rb[c], aR[3][c]);
            aT[0][c] = fmaf(a0, tb[c], aT[0][c]); aT[1][c] = fmaf(a1, tb[c], aT[1][c]);
            aT[2][c] = fmaf(a2, tb[c], aT[2][c]); aT[3][c] = fmaf(a3, tb[c], aT[3][c]);
        }
    }
#pragma unroll
    for (int r = 0; r < 4; ++r) {
        int row = blk * 64 + tm * 4 + r;
        float4 vr = make_float4(aR[r][0], aR[r][1], aR[r][2], aR[r][3]);
        float4 vt = make_float4(aT[r][0], aT[r][1], aT[r][2], aT[r][3]);
        if (FIRST) {
            int ii = isoIdx[row];
            float4 er = *(const float4*)(WrelIso + (size_t)ii * 64 + tn * 4);
            float4 et = *(const float4*)(WrootIso + (size_t)ii * 64 + tn * 4);
            vr.x += er.x; vr.y += er.y; vr.z += er.z; vr.w += er.w;
            vt.x += et.x; vt.y += et.y; vt.z += et.z; vt.w += et.w;
        }
        *(float4*)(Yrel + (size_t)row * 64 + tn * 4) = vr;
        *(float4*)(Yroot + (size_t)row * 64 + tn * 4) = vt;
    }
}

// ---------------- GraphConv gather: clamped masked chunk-4 (lambda=4) + col prefetch ----------------
__global__ void kgather2(const float* __restrict__ yrel, const float* __restrict__ yroot,
                         const float* __restrict__ brel, const int* __restrict__ offs,
                         const int* __restrict__ col, float* __restrict__ out) {
    int t = blockIdx.x * 256 + threadIdx.x;
    int j = t >> 4, c = t & 15;
    int s0 = offs[j], s1 = offs[j + 1];
    float4 rt = *(const float4*)(yroot + (size_t)j * 64 + 4 * c);
    float4 bb = *(const float4*)(brel + 4 * c);
    float a0 = rt.x + bb.x, a1 = rt.y + bb.y, a2 = rt.z + bb.z, a3 = rt.w + bb.w;
    if (s0 < s1) {
        int vv[4];
#pragma unroll
        for (int jj = 0; jj < 4; ++jj) {
            int idx = s0 + jj; idx = idx < s1 ? idx : s1 - 1;
            vv[jj] = col[idx];
        }
        int e = s0;
        while (true) {
            int ne = e + 4;
            bool more = ne < s1;
            float4 xs[4];
#pragma unroll
            for (int jj = 0; jj < 4; ++jj)
                xs[jj] = *(const float4*)(yrel + (size_t)vv[jj] * 64 + 4 * c);
            int nx[4];
            if (more) {
#pragma unroll
                for (int jj = 0; jj < 4; ++jj) {
                    int idx = ne + jj; idx = idx < s1 ? idx : s1 - 1;
                    nx[jj] = col[idx];
                }
            }
#pragma unroll
            for (int jj = 0; jj < 4; ++jj) {
                float mm = (e + jj < s1) ? 1.f : 0.f;
                a0 = fmaf(xs[jj].x, mm, a0);
                a1 = fmaf(xs[jj].y, mm, a1);
                a2 = fmaf(xs[jj].z, mm, a2);
                a3 = fmaf(xs[jj].w, mm, a3);
            }
            if (!more) break;
            e = ne;
#pragma unroll
            for (int jj = 0; jj < 4; ++jj) vv[jj] = nx[jj];
        }
    }
    *(float4*)(out + (size_t)j * 64 + 4 * c) =
        make_float4(fmaxf(a0, 0.f), fmaxf(a1, 0.f), fmaxf(a2, 0.f), fmaxf(a3, 0.f));
}

// ---------------- per-graph mean pools (x1 gets final BN affine on the mean) ----------------
__global__ void kpoolg(const float* __restrict__ h2, const float* __restrict__ xp2,
                       const float* __restrict__ pst, const float* __restrict__ g4,
                       const float* __restrict__ b4, float* __restrict__ m) {
    __shared__ float sstat[128];
    __shared__ float red[4][64];
    int g = blockIdx.x, tid = threadIdx.x;
    if (tid < 128) {
        float s = 0.f;
        const float* p = pst + tid;
#pragma unroll
        for (int i = 0; i < 32; ++i) s += p[i * 128];
        sstat[tid] = s;
    }
    int wid = tid >> 6, d = tid & 63;
    float s1 = 0.f;
    for (int i = wid; i < 200; i += 4) s1 += h2[((size_t)g * 200 + i) * 64 + d];
    red[wid][d] = s1;
    __syncthreads();
    if (wid == 0) {
        float mean = (red[0][d] + red[1][d] + red[2][d] + red[3][d]) * (1.f / 200.f);
        float mu = sstat[d] * (1.f / NN);
        float var = sstat[64 + d] * (1.f / NN) - mu * mu;
        float sc = g4[d] * rsqrtf(var + 1e-5f);
        m[g * 128 + d] = fmaf(mean, sc, b4[d] - mu * sc);
    }
    __syncthreads();
    float s2 = 0.f;
    for (int i = wid; i < 400; i += 4) s2 += xp2[((size_t)g * 400 + i) * 64 + d];
    red[wid][d] = s2;
    __syncthreads();
    if (wid == 0) m[g * 128 + 64 + d] = (red[0][d] + red[1][d] + red[2][d] + red[3][d]) * (1.f / 400.f);
}

// ---------------- readout MLP ----------------
__global__ void kread(const float* __restrict__ m, const float* __restrict__ W0,
                      const float* __restrict__ b0, const float* __restrict__ W1,
                      const float* __restrict__ b1, const float* __restrict__ W2,
                      const float* __restrict__ b2, const float* __restrict__ lw,
                      const float* __restrict__ lb, float* __restrict__ out) {
    __shared__ float s0[64], s1[32], s2[16];
    int g = blockIdx.x, d = threadIdx.x;
    const float* mr = m + g * 128;
    float t = b0[d];
    for (int k = 0; k < 128; ++k) t = fmaf(mr[k], W0[k * 64 + d], t);
    s0[d] = fmaxf(t, 0.f);
    __syncthreads();
    if (d < 32) {
        float u = b1[d];
        for (int k = 0; k < 64; ++k) u = fmaf(s0[k], W1[k * 32 + d], u);
        s1[d] = fmaxf(u, 0.f);
    }
    __syncthreads();
    if (d < 16) {
        float u = b2[d];
        for (int k = 0; k < 32; ++k) u = fmaf(s1[k], W2[k * 16 + d], u);
        s2[d] = fmaxf(u, 0.f);
    }
    __syncthreads();
    if (d == 0) {
        float u = lb[0];
        for (int k = 0; k < 16; ++k) u = fmaf(s2[k], lw[k], u);
        out[g] = u;
    }
}

// ---------------- host ----------------
extern "C" void kernel_launch(void* const* d_in, const int* in_sizes, int n_in,
                              void* d_out, int out_size, void* d_ws, size_t ws_size,
                              hipStream_t stream) {
    if (ws_size < WS_NEEDED) return;

    const float* x    = (const float*)d_in[0];
    const int*   ei   = (const int*)d_in[1];
    const int*   ea   = (const int*)d_in[2];
    const float* iso  = (const float*)d_in[4];
    const int*   ei2  = (const int*)d_in[5];
    const int*   ai2  = (const int*)d_in[6];
    const float* embW = (const float*)d_in[8];
    const float* embB = (const float*)d_in[9];
    const float* gW1  = (const float*)d_in[10];
    const float* gB1  = (const float*)d_in[11];
    const float* gW2  = (const float*)d_in[12];
    const float* gB2  = (const float*)d_in[13];
    const float* ee1  = (const float*)d_in[14];
    const float* ee2  = (const float*)d_in[15];
    const float* bng  = (const float*)d_in[16];
    const float* bnb  = (const float*)d_in[17];
    const float* i1rW = (const float*)d_in[18];
    const float* i1rB = (const float*)d_in[19];
    const float* i1tW = (const float*)d_in[20];
    const float* i2rW = (const float*)d_in[21];
    const float* i2rB = (const float*)d_in[22];
    const float* i2tW = (const float*)d_in[23];
    const float* roW0 = (const float*)d_in[24];
    const float* roB0 = (const float*)d_in[25];
    const float* roW1 = (const float*)d_in[26];
    const float* roB1 = (const float*)d_in[27];
    const float* roW2 = (const float*)d_in[28];
    const float* roB2 = (const float*)d_in[29];
    const float* lW   = (const float*)d_in[30];
    const float* lB   = (const float*)d_in[31];
    float* out = (float*)d_out;

    char* ws = (char*)d_ws;
    float* h      = (float*)(ws + OFF_H);
    float* hB     = (float*)(ws + OFF_AGG);    // ping-pong buffer B
    float* hA     = (float*)(ws + OFF_H2);     // ping-pong buffer A; final h2
    float* h2     = hA;
    float* xp     = (float*)(ws + OFF_XP);
    float* yrel   = (float*)(ws + OFF_H);      // spans h+hB (both dead post-GIN)
    float* yroot  = (float*)(ws + OFF_YROOT);
    int* offs1    = (int*)(ws + OFF_OFFS1);
    int* col1     = (int*)(ws + OFF_COL1);
    int* offs2    = (int*)(ws + OFF_OFFS2);
    int* col2     = (int*)(ws + OFF_COL2);
    int* cnt1     = (int*)(ws + OFF_CNT1);
    int* cnt2     = (int*)(ws + OFF_CNT2);
    int* isoIdx   = (int*)(ws + OFF_ISO);
    float* mbuf   = (float*)(ws + OFF_M);
    int* bsum1    = (int*)(ws + OFF_M);
    int* boffs1   = (int*)(ws + OFF_M + 256);
    int* bsum2    = (int*)(ws + OFF_M + 512);
    int* boffs2   = (int*)(ws + OFF_M + 1024);
    ushort_t* w1h = (ushort_t*)(ws + OFF_YROOT);
    ushort_t* w1l = (ushort_t*)(ws + OFF_YROOT + 81920);
    ushort_t* w2h = (ushort_t*)(ws + OFF_YROOT + 163840);
    ushort_t* w2l = (ushort_t*)(ws + OFF_YROOT + 245760);
    float* pstat2 = (float*)(ws + OFF_CUR1);   // zeroed by memset each launch
    int* rank1    = (int*)(ws + OFF_XP);       // xp region: ranks during CSR build
    int* rank2    = (int*)(ws + OFF_XP + (size_t)EE * 4);
    int* perm     = (int*)(ws + OFF_PERM);     // non-aliasing: allows kfill2 fusion; dead before xp writes
    int* dbin     = (int*)(ws + OFF_STATS);    // zeroed
    int* dstart   = dbin + 64;
    int* dcur     = dbin + 128;

    const int* src1 = ei;
    const int* dst1 = ei + EE;
    const int* src2 = ei2;
    const int* dst2 = ei2 + EE2;
    const int* a0   = ai2;

    hipMemsetAsync(ws + OFF_CNT1, 0, ZERO_BYTES, stream);

    // CSR build: histogram (atomic-bound, kept lean) then independent prep work
    khist_m<<<1200, 256, 0, stream>>>(dst1, dst2, cnt1, cnt2, rank1, rank2);
    kprepx<<<13240, 256, 0, stream>>>(x, embW, embB, h, gW1, gW2,
                                      w1h, w1l, w2h, w2l, iso, isoIdx);
    kreduce_m<<<150, 256, 0, stream>>>(cnt1, cnt2, bsum1, bsum2);
    kscan_small_m<<<2, 128, 0, stream>>>(bsum1, bsum2, boffs1, boffs2);
    kscan_apply_m<<<150, 256, 0, stream>>>(cnt1, cnt2, boffs1, boffs2, offs1, offs2, dbin);
    kdegscan<<<1, 64, 0, stream>>>(dbin, dstart);
    // fused: CSR fill + degree-sort placement (perm does not alias rank1)
    kfill2<<<1400, 256, 0, stream>>>(src1, dst1, ea, rank1, offs1, col1,
                                     src2, dst2, rank2, offs2, col2,
                                     dstart, dcur, perm);

    // GIN layers: fused gather+MLP, h ping-pong (layer 4 lands in hA = h2);
    // ktrans applies BN+ReLU per node between layers (layer-4 output stays raw for the branch)
    for (int l = 0; l < LL; ++l) {
        const float* hin = (l == 0) ? h : ((l & 1) ? hA : hB);
        float* hout = (l & 1) ? hB : hA;
        kglayer<<<NN / 16, 256, 0, stream>>>(
            hin, hout, perm, offs1, col1, ee1 + l * 384, ee2 + l * 192,
            w1h + (size_t)l * 8192, w1l + (size_t)l * 8192,
            w2h + (size_t)l * 8192, w2l + (size_t)l * 8192,
            gB1 + l * 128, gB2 + l * 64,
            pstat2 + (size_t)l * 4096);
        if (l < LL - 1)
            ktrans<<<800, 256, 0, stream>>>(hout, pstat2 + (size_t)l * 4096,
                                            bng + l * 64, bnb + l * 64);
    }

    // 2-set branch (avg-pool + final-layer BN fused into kgcmm<1> staging; kpoolg folds BN on mean)
    kgcmm<1><<<NN2 / 64, 256, 0, stream>>>(xp, i1rW, i1tW, i1rW + 64 * 64,
                                           i1tW + 64 * 64, isoIdx, yrel, yroot,
                                           pstat2 + (size_t)4 * 4096,
                                           bng + 4 * 64, bnb + 4 * 64, a0, h2);
    kgather2<<<NN2 * 16 / 256, 256, 0, stream>>>(yrel, yroot, i1rB, offs2, col2, xp);
    kgcmm<0><<<NN2 / 64, 256, 0, stream>>>(xp, i2rW, i2tW, nullptr, nullptr,
                                           nullptr, yrel, yroot,
                                           nullptr, nullptr, nullptr, nullptr, nullptr);
    kgather2<<<NN2 * 16 / 256, 256, 0, stream>>>(yrel, yroot, i2rB, offs2, col2, xp);

    // pools + readout
    kpoolg<<<GG, 256, 0, stream>>>(h2, xp, pstat2 + (size_t)4 * 4096,
                                   bng + 4 * 64, bnb + 4 * 64, mbuf);
    kread<<<GG, 64, 0, stream>>>(mbuf, roW0, roB0, roW1, roB1, roW2, roB2, lW, lB, out);
}

// Round 6
// 591.497 us; speedup vs baseline: 1.0524x; 1.0524x over previous
//
#include <hip/hip_runtime.h>

#define NN   51200
#define EE   819200
#define GG   256
#define NN2  102400
#define AA   204800
#define EE2  409600
#define DD   64
#define LL   5

// bucket CSR build
#define NB1  100
#define NB2  200
#define CAP1 10240
#define CAP2 3072

typedef __attribute__((ext_vector_type(8))) short bf16x8;
typedef __attribute__((ext_vector_type(4))) float f32x4;
typedef unsigned short ushort_t;

// ---------------- workspace layout (bytes) ----------------
#define OFF_H      ((size_t)0)          // emb h; post-GIN: yrel spans OFF_H..OFF_H2
#define OFF_AGG    ((size_t)13107200)   // GIN: h ping-pong buffer B
#define OFF_H2     ((size_t)26214400)   // GIN: buffer A; layer-4 output = h2 (alive to kpoolg)
#define OFF_XP     ((size_t)39321600)   // rec1/rec2 during CSR build; later xp
#define OFF_REC1   OFF_XP                       // 100*10240*8 = 8,192,000
#define OFF_REC2   ((size_t)47513600)           // 200*3072*8  = 4,915,200 (ends 52,428,800)
#define OFF_PERM   ((size_t)60293120)   // perm (200KB) inside xp region; dead before kgather2 writes xp
#define OFF_YROOT  ((size_t)65536000)   // prepped bf16 weights during GIN; yroot after
#define OFF_OFFS1  ((size_t)91750400)
#define OFF_COL1   ((size_t)91955216)
#define OFF_OFFS2  ((size_t)95232016)
#define OFF_COL2   ((size_t)95641632)
#define OFF_CNT1   ((size_t)97280032)   // zeroed region starts here; bucketCnt[300] lives here
#define OFF_BBASE  ((size_t)97282080)   // bucketBase[300] (inside zeroed region, harmless)
#define OFF_CUR1   ((size_t)97484832)   // pstat2[5][32][128] during GIN (zeroed by memset)
#define OFF_STATS  ((size_t)98508832)   // dbin[64], dstart[64], dcur[64] (zeroed)
#define ZERO_BYTES ((size_t)1231360)
#define OFF_ISO    ((size_t)98511392)
#define OFF_M      ((size_t)98920992)
#define WS_NEEDED  ((size_t)99052064)

__device__ __forceinline__ int waveInclScan(int v, int lane) {
#pragma unroll
    for (int off = 1; off < 64; off <<= 1) {
        int t = __shfl_up(v, off, 64);
        if (lane >= off) v += t;
    }
    return v;
}

// ---------------- split-bf16 helpers ----------------
__device__ __forceinline__ void bsplit(float x, ushort_t& hi, ushort_t& lo) {
    union { float f; unsigned u; } a; a.f = x;
    unsigned hb = (a.u + 0x7FFFu + ((a.u >> 16) & 1u)) >> 16;   // RNE to bf16
    union { unsigned u; float f; } h; h.u = hb << 16;
    float r = x - h.f;
    union { float f; unsigned u; } b; b.f = r;
    unsigned lb = (b.u + 0x7FFFu + ((b.u >> 16) & 1u)) >> 16;
    hi = (ushort_t)hb; lo = (ushort_t)lb;
}

// ---------------- bucket build phase A: scatter edges by dst>>9 ----------------
// Per-edge rank via LDS atomic (fast); ONE returning global atomic per (block,bin)
// (90K total vs 1.23M in the old khist). Records land in fixed-capacity bucket regions.
__global__ __launch_bounds__(256) void kbA(const int* __restrict__ src1, const int* __restrict__ dst1,
                                           const int* __restrict__ ea,
                                           const int* __restrict__ src2, const int* __restrict__ dst2,
                                           int* __restrict__ bucketCnt,
                                           int2* __restrict__ rec1, int2* __restrict__ rec2) {
    __shared__ int lhist[256];
    __shared__ int lbase[256];
    int tid = threadIdx.x, b = blockIdx.x;
    lhist[tid] = 0;
    __syncthreads();
    if (b < 400) {
        int i = (b * 256 + tid) * 8;
        int4 d0 = *(const int4*)(dst1 + i);
        int4 d1 = *(const int4*)(dst1 + i + 4);
        int dst[8] = {d0.x, d0.y, d0.z, d0.w, d1.x, d1.y, d1.z, d1.w};
        int bin[8], lr[8];
#pragma unroll
        for (int j = 0; j < 8; ++j) {
            bin[j] = dst[j] >> 9;
            lr[j] = atomicAdd(&lhist[bin[j]], 1);
        }
        __syncthreads();
        if (tid < NB1) {
            int c = lhist[tid];
            lbase[tid] = c ? atomicAdd(&bucketCnt[tid], c) : 0;
        }
        __syncthreads();
        int4 s0 = *(const int4*)(src1 + i);
        int4 s1 = *(const int4*)(src1 + i + 4);
        int src[8] = {s0.x, s0.y, s0.z, s0.w, s1.x, s1.y, s1.z, s1.w};
        int4 e0 = *(const int4*)(ea + 2 * i);
        int4 e1 = *(const int4*)(ea + 2 * i + 4);
        int4 e2 = *(const int4*)(ea + 2 * i + 8);
        int4 e3 = *(const int4*)(ea + 2 * i + 12);
        int code[8] = {e0.x * 3 + e0.y, e0.z * 3 + e0.w, e1.x * 3 + e1.y, e1.z * 3 + e1.w,
                       e2.x * 3 + e2.y, e2.z * 3 + e2.w, e3.x * 3 + e3.y, e3.z * 3 + e3.w};
#pragma unroll
        for (int j = 0; j < 8; ++j) {
            int pos = bin[j] * CAP1 + lbase[bin[j]] + lr[j];
            rec1[pos] = make_int2(src[j] | (code[j] << 16), dst[j]);
        }
    } else {
        int i = ((b - 400) * 256 + tid) * 8;
        int4 d0 = *(const int4*)(dst2 + i);
        int4 d1 = *(const int4*)(dst2 + i + 4);
        int dst[8] = {d0.x, d0.y, d0.z, d0.w, d1.x, d1.y, d1.z, d1.w};
        int bin[8], lr[8];
#pragma unroll
        for (int j = 0; j < 8; ++j) {
            bin[j] = dst[j] >> 9;
            lr[j] = atomicAdd(&lhist[bin[j]], 1);
        }
        __syncthreads();
        if (tid < NB2) {
            int c = lhist[tid];
            lbase[tid] = c ? atomicAdd(&bucketCnt[NB1 + tid], c) : 0;
        }
        __syncthreads();
        int4 s0 = *(const int4*)(src2 + i);
        int4 s1 = *(const int4*)(src2 + i + 4);
        int src[8] = {s0.x, s0.y, s0.z, s0.w, s1.x, s1.y, s1.z, s1.w};
#pragma unroll
        for (int j = 0; j < 8; ++j) {
            int pos = bin[j] * CAP2 + lbase[bin[j]] + lr[j];
            rec2[pos] = make_int2(src[j], dst[j]);
        }
    }
}

// exclusive scan of bucket counts (block 0: g1's 100, block 1: g2's 200)
__global__ void kbscan(const int* __restrict__ bucketCnt, int* __restrict__ bucketBase) {
    __shared__ int wsum[4];
    int tid = threadIdx.x, lane = tid & 63, wid = tid >> 6;
    int nb = blockIdx.x ? NB2 : NB1;
    const int* cnt = bucketCnt + (blockIdx.x ? NB1 : 0);
    int* base = bucketBase + (blockIdx.x ? NB1 : 0);
    int v = (tid < nb) ? cnt[tid] : 0;
    int incl = waveInclScan(v, lane);
    if (lane == 63) wsum[wid] = incl;
    __syncthreads();
    int woff = 0;
#pragma unroll
    for (int w = 0; w < 3; ++w) woff += (w < wid) ? wsum[w] : 0;
    if (tid < nb) base[tid] = woff + incl - v;
}

// ---------------- bucket build phase B: per-bucket CSR (LDS hist + scan + place) ----------------
// Also writes offs and the g1 degree histogram for the counting sort. All per-edge atomics are LDS.
__global__ __launch_bounds__(256) void kbB(const int* __restrict__ bucketCnt,
                                           const int* __restrict__ bucketBase,
                                           const int2* __restrict__ rec1, const int2* __restrict__ rec2,
                                           int* __restrict__ offs1, int* __restrict__ col1,
                                           int* __restrict__ offs2, int* __restrict__ col2,
                                           int* __restrict__ dbin) {
    __shared__ int nh[512];
    __shared__ int ncur[512];
    __shared__ int wsum[4];
    __shared__ int dhist[64];
    int tid = threadIdx.x, b = blockIdx.x;
    bool g1 = b < NB1;
    const int2* rec = g1 ? (rec1 + (size_t)b * CAP1) : (rec2 + (size_t)(b - NB1) * CAP2);
    int cnt = bucketCnt[b];
    int base = bucketBase[b];
    int* offs = g1 ? offs1 : offs2;
    int* col = g1 ? col1 : col2;
    int nodeBase = g1 ? b * 512 : (b - NB1) * 512;
    nh[tid] = 0; nh[tid + 256] = 0;
    if (tid < 64) dhist[tid] = 0;
    __syncthreads();
    for (int e = tid; e < cnt; e += 256) {
        int2 r = rec[e];
        atomicAdd(&nh[r.y & 511], 1);
    }
    __syncthreads();
    int v0 = nh[2 * tid], v1 = nh[2 * tid + 1];
    int s = v0 + v1;
    int lane = tid & 63, wid = tid >> 6;
    int incl = waveInclScan(s, lane);
    if (lane == 63) wsum[wid] = incl;
    __syncthreads();
    int woff = 0;
#pragma unroll
    for (int w = 0; w < 3; ++w) woff += (w < wid) ? wsum[w] : 0;
    int excl = woff + incl - s;
    ncur[2 * tid] = excl;
    ncur[2 * tid + 1] = excl + v0;
    offs[nodeBase + 2 * tid] = base + excl;
    offs[nodeBase + 2 * tid + 1] = base + excl + v0;
    if (g1) {
        atomicAdd(&dhist[v0 < 63 ? v0 : 63], 1);
        atomicAdd(&dhist[v1 < 63 ? v1 : 63], 1);
    }
    __syncthreads();
    for (int e = tid; e < cnt; e += 256) {
        int2 r = rec[e];
        int node = r.y & 511;
        int slot = base + atomicAdd(&ncur[node], 1);
        col[slot] = r.x;
    }
    if (g1 && tid < 64 && dhist[tid]) atomicAdd(&dbin[tid], dhist[tid]);
    if (tid == 0) {
        if (b == NB1 - 1) offs1[NN] = EE;
        if (b == NB1 + NB2 - 1) offs2[NN2] = EE2;
    }
}

// ---------------- prep: embedding + weight prep + iso argmax ----------------
__global__ void kprepx(const float* __restrict__ x, const float* __restrict__ embW,
                       const float* __restrict__ embB, float* __restrict__ h,
                       const float* __restrict__ gW1, const float* __restrict__ gW2,
                       ushort_t* __restrict__ w1h, ushort_t* __restrict__ w1l,
                       ushort_t* __restrict__ w2h, ushort_t* __restrict__ w2l,
                       const float* __restrict__ iso, int* __restrict__ isoIdx) {
    int b = blockIdx.x;
    if (b < 12800) {
        int t = b * 256 + threadIdx.x;
        int n = t >> 6, d = t & 63;
        float acc = embB[d];
        const float* xr = x + n * 40;
#pragma unroll
        for (int k = 0; k < 40; ++k) acc = fmaf(xr[k], embW[k * 64 + d], acc);
        h[(size_t)n * 64 + d] = fmaxf(acc, 0.f);
    } else if (b < 12840) {
        int t = (b - 12800) * 256 + threadIdx.x;
        int lane = t & 63, frag = t >> 6;
        int c15 = lane & 15, q = lane >> 4;
        if (frag < 80) {
            int kt = frag & 1, nt = (frag >> 1) & 7, l = frag >> 4;
            const float* W = gW1 + l * 8192;
            ushort_t* oh = w1h + ((size_t)frag * 64 + lane) * 8;
            ushort_t* ol = w1l + ((size_t)frag * 64 + lane) * 8;
            int kb = kt * 32 + q * 8, colw = nt * 16 + c15;
#pragma unroll
            for (int j = 0; j < 8; ++j) {
                ushort_t hi, lo; bsplit(W[(kb + j) * 128 + colw], hi, lo);
                oh[j] = hi; ol[j] = lo;
            }
        } else if (frag < 160) {
            int f = frag - 80;
            int kt = f & 3, nt = (f >> 2) & 3, l = f >> 4;
            const float* W = gW2 + l * 8192;
            ushort_t* oh = w2h + ((size_t)f * 64 + lane) * 8;
            ushort_t* ol = w2l + ((size_t)f * 64 + lane) * 8;
            int kb = kt * 32 + q * 8, colw = nt * 16 + c15;
#pragma unroll
            for (int j = 0; j < 8; ++j) {
                ushort_t hi, lo; bsplit(W[(kb + j) * 64 + colw], hi, lo);
                oh[j] = hi; ol[j] = lo;
            }
        }
    } else {
        int j = (b - 12840) * 256 + threadIdx.x;
        const float4* r4 = (const float4*)(iso + (size_t)j * 36);
        int best = 0;
#pragma unroll
        for (int k = 0; k < 9; ++k) {
            float4 v = r4[k];
            if (v.x > 0.5f) best = 4 * k;
            if (v.y > 0.5f) best = 4 * k + 1;
            if (v.z > 0.5f) best = 4 * k + 2;
            if (v.w > 0.5f) best = 4 * k + 3;
        }
        isoIdx[j] = best;
    }
}

// ASCENDING placement (R3/R4 behavior — measured faster than descending)
__global__ void kdegscan(const int* __restrict__ dbin, int* __restrict__ dstart) {
    int tid = threadIdx.x;
    int v = dbin[tid];
    int incl = waveInclScan(v, tid);
    dstart[tid] = incl - v;
}

// two-level counting-sort placement: LDS-local ranks + one global atomic per (block,bin)
__global__ __launch_bounds__(256) void kdegplace(const int* __restrict__ offs,
                                                 const int* __restrict__ dstart,
                                                 int* __restrict__ dcur,
                                                 int* __restrict__ perm) {
    __shared__ int lhist[64];
    __shared__ int lbase[64];
    int tid = threadIdx.x;
    if (tid < 64) lhist[tid] = 0;
    __syncthreads();
    int n = blockIdx.x * 256 + tid;
    int d = offs[n + 1] - offs[n]; d = d < 63 ? d : 63;
    int lr = atomicAdd(&lhist[d], 1);
    __syncthreads();
    if (tid < 64) {
        int c = lhist[tid];
        lbase[tid] = c ? atomicAdd(&dcur[tid], c) : 0;
    }
    __syncthreads();
    perm[dstart[d] + lbase[d] + lr] = n;
}

// ---------------- per-node BN+ReLU transform, in place (once per node, not per edge) ----------------
__global__ __launch_bounds__(256) void ktrans(float* __restrict__ h,
                                              const float* __restrict__ pst,
                                              const float* __restrict__ gamma,
                                              const float* __restrict__ beta) {
    __shared__ float sstat[128];
    __shared__ float sSC[64], sSH[64];
    int tid = threadIdx.x;
    if (tid < 128) {
        float s = 0.f;
        const float* p = pst + tid;
#pragma unroll
        for (int i = 0; i < 32; ++i) s += p[i * 128];
        sstat[tid] = s;
    }
    __syncthreads();
    if (tid < 64) {
        float mu = sstat[tid] * (1.f / NN);
        float var = sstat[64 + tid] * (1.f / NN) - mu * mu;
        float sc = gamma[tid] * rsqrtf(var + 1e-5f);
        sSC[tid] = sc; sSH[tid] = beta[tid] - mu * sc;
    }
    __syncthreads();
    int c = (tid & 15) * 4;
    float4 sc4 = *(const float4*)(sSC + c);
    float4 sh4 = *(const float4*)(sSH + c);
    float4* hp = (float4*)h;
    size_t base = (size_t)blockIdx.x * 1024 + tid;
#pragma unroll
    for (int r = 0; r < 4; ++r) {
        float4 v = hp[base + r * 256];
        v.x = fmaxf(fmaf(v.x, sc4.x, sh4.x), 0.f);
        v.y = fmaxf(fmaf(v.y, sc4.y, sh4.y), 0.f);
        v.z = fmaxf(fmaf(v.z, sc4.z, sh4.z), 0.f);
        v.w = fmaxf(fmaf(v.w, sc4.w, sh4.w), 0.f);
        hp[base + r * 256] = v;
    }
}

// ---------------- fused GIN layer: gather(16 perm'd nodes) -> LDS -> MFMA MLP -> hout + stats ----
__global__ __launch_bounds__(256) void kglayer(
    const float* __restrict__ hin, float* __restrict__ hout,
    const int* __restrict__ perm,
    const int* __restrict__ offs, const int* __restrict__ col,
    const float* __restrict__ e1, const float* __restrict__ e2,
    const ushort_t* __restrict__ w1h, const ushort_t* __restrict__ w1l,
    const ushort_t* __restrict__ w2h, const ushort_t* __restrict__ w2l,
    const float* __restrict__ b1, const float* __restrict__ b2,
    float* __restrict__ pstout) {
    __shared__ float etab[13 * 64];
    __shared__ int sPerm[16];
    __shared__ float sMLP[16 * 132];   // sA stride-68 aliases front; sH stride-132
    float* sA = sMLP;
    float* sH = sMLP;
    int tid = threadIdx.x;
    if (tid < 16) sPerm[tid] = perm[blockIdx.x * 16 + tid];
    for (int idx = tid; idx < 13 * 64; idx += 256) {
        int ci = idx >> 6, dd = idx & 63;
        etab[idx] = e1[(ci / 3) * 64 + dd] + e2[(ci % 3) * 64 + dd];
    }
    __syncthreads();
    int lane = tid & 63, wv = tid >> 6;
    int c15 = lane & 15, q = lane >> 4;

    // ---- gather node n into sA ----
    {
        int n = sPerm[wv * 4 + q];
        int s0 = offs[n], s1 = offs[n + 1];
        float4 sx = *(const float4*)(hin + (size_t)n * 64 + 4 * c15);
        float4 et = *(const float4*)(etab + 12 * 64 + 4 * c15);
        float a0 = sx.x + et.x, a1 = sx.y + et.y, a2 = sx.z + et.z, a3 = sx.w + et.w;
        int deg = s1 - s0;
        if (deg > 0) {
            const int* cp = col + s0;
            int nfull = deg >> 3, rem = deg & 7;
            int vv[8];
#pragma unroll
            for (int j = 0; j < 8; ++j) {
                int idx = j < deg ? j : deg - 1;
                vv[j] = cp[idx];
            }
            for (int it = 0; it < nfull; ++it) {
                float4 xv[8], tv[8];
#pragma unroll
                for (int j = 0; j < 8; ++j) {
                    xv[j] = *(const float4*)(hin + (size_t)(vv[j] & 0xFFFF) * 64 + 4 * c15);
                    tv[j] = *(const float4*)(etab + (vv[j] >> 16) * 64 + 4 * c15);
                }
                int e8 = (it + 1) * 8;
                bool more = e8 < deg;
                int nx[8];
                if (more) {
#pragma unroll
                    for (int j = 0; j < 8; ++j) {
                        int idx = e8 + j; idx = idx < deg ? idx : deg - 1;
                        nx[j] = cp[idx];
                    }
                }
#pragma unroll
                for (int j = 0; j < 8; ++j) {
                    a0 += xv[j].x + tv[j].x;
                    a1 += xv[j].y + tv[j].y;
                    a2 += xv[j].z + tv[j].z;
                    a3 += xv[j].w + tv[j].w;
                }
                if (more) {
#pragma unroll
                    for (int j = 0; j < 8; ++j) vv[j] = nx[j];
                }
            }
            if (rem) {
                float4 xv[8], tv[8];
#pragma unroll
                for (int j = 0; j < 8; ++j) {
                    xv[j] = *(const float4*)(hin + (size_t)(vv[j] & 0xFFFF) * 64 + 4 * c15);
                    tv[j] = *(const float4*)(etab + (vv[j] >> 16) * 64 + 4 * c15);
                }
#pragma unroll
                for (int j = 0; j < 8; ++j) {
                    float mm = (j < rem) ? 1.f : 0.f;
                    a0 = fmaf(xv[j].x + tv[j].x, mm, a0);
                    a1 = fmaf(xv[j].y + tv[j].y, mm, a1);
                    a2 = fmaf(xv[j].z + tv[j].z, mm, a2);
                    a3 = fmaf(xv[j].w + tv[j].w, mm, a3);
                }
            }
        }
        *(float4*)(sA + (wv * 4 + q) * 68 + 4 * c15) = make_float4(a0, a1, a2, a3);
    }
    __syncthreads();

    // ---- A-frags to regs (sA dies after next sync; sH aliases) ----
    bf16x8 ah[2], al[2];
#pragma unroll
    for (int kt = 0; kt < 2; ++kt) {
        const float* p = sA + c15 * 68 + kt * 32 + q * 8;
        float4 x0 = *(const float4*)p;
        float4 x1 = *(const float4*)(p + 4);
        float xs[8] = {x0.x, x0.y, x0.z, x0.w, x1.x, x1.y, x1.z, x1.w};
#pragma unroll
        for (int j = 0; j < 8; ++j) {
            ushort_t hi, lo; bsplit(xs[j], hi, lo);
            ah[kt][j] = (short)hi; al[kt][j] = (short)lo;
        }
    }
    __syncthreads();

    // ---- GEMM1: nt = 2wv+j ----
    f32x4 acc1[2];
#pragma unroll
    for (int j = 0; j < 2; ++j) { f32x4 z = {0.f, 0.f, 0.f, 0.f}; acc1[j] = z; }
#pragma unroll
    for (int kt = 0; kt < 2; ++kt) {
#pragma unroll
        for (int j = 0; j < 2; ++j) {
            int nt = 2 * wv + j;
            size_t fo = ((size_t)((nt * 2 + kt) * 64 + lane)) * 8;
            bf16x8 bh = *(const bf16x8*)(w1h + fo);
            bf16x8 bl = *(const bf16x8*)(w1l + fo);
            acc1[j] = __builtin_amdgcn_mfma_f32_16x16x32_bf16(ah[kt], bh, acc1[j], 0, 0, 0);
            acc1[j] = __builtin_amdgcn_mfma_f32_16x16x32_bf16(al[kt], bh, acc1[j], 0, 0, 0);
            acc1[j] = __builtin_amdgcn_mfma_f32_16x16x32_bf16(ah[kt], bl, acc1[j], 0, 0, 0);
        }
    }
#pragma unroll
    for (int j = 0; j < 2; ++j) {
        int nt = 2 * wv + j;
        float bias = b1[nt * 16 + c15];
#pragma unroll
        for (int rg = 0; rg < 4; ++rg)
            sH[(4 * q + rg) * 132 + nt * 16 + c15] = fmaxf(acc1[j][rg] + bias, 0.f);
    }
    __syncthreads();

    // ---- GEMM2: nt = wv ----
    f32x4 acc2 = {0.f, 0.f, 0.f, 0.f};
#pragma unroll
    for (int kt = 0; kt < 4; ++kt) {
        const float* p = sH + c15 * 132 + kt * 32 + q * 8;
        float4 x0 = *(const float4*)p;
        float4 x1 = *(const float4*)(p + 4);
        float xs[8] = {x0.x, x0.y, x0.z, x0.w, x1.x, x1.y, x1.z, x1.w};
        bf16x8 a2h, a2l;
#pragma unroll
        for (int j = 0; j < 8; ++j) {
            ushort_t hi, lo; bsplit(xs[j], hi, lo);
            a2h[j] = (short)hi; a2l[j] = (short)lo;
        }
        size_t fo = ((size_t)((wv * 4 + kt) * 64 + lane)) * 8;
        bf16x8 bh = *(const bf16x8*)(w2h + fo);
        bf16x8 bl = *(const bf16x8*)(w2l + fo);
        acc2 = __builtin_amdgcn_mfma_f32_16x16x32_bf16(a2h, bh, acc2, 0, 0, 0);
        acc2 = __builtin_amdgcn_mfma_f32_16x16x32_bf16(a2l, bh, acc2, 0, 0, 0);
        acc2 = __builtin_amdgcn_mfma_f32_16x16x32_bf16(a2h, bl, acc2, 0, 0, 0);
    }
    {
        float bias = b2[wv * 16 + c15];
        float s = 0.f, s2 = 0.f;
#pragma unroll
        for (int rg = 0; rg < 4; ++rg) {
            float v = acc2[rg] + bias;
            hout[(size_t)sPerm[4 * q + rg] * 64 + wv * 16 + c15] = v;
            s += v; s2 += v * v;
        }
        s += __shfl_xor(s, 16, 64);  s += __shfl_xor(s, 32, 64);
        s2 += __shfl_xor(s2, 16, 64); s2 += __shfl_xor(s2, 32, 64);
        if (q == 0) {
            float* ps = pstout + (size_t)(blockIdx.x & 31) * 128;
            atomicAdd(&ps[wv * 16 + c15], s);
            atomicAdd(&ps[64 + wv * 16 + c15], s2);
        }
    }
}

// ---------------- GraphConv GEMMs; FIRST fuses 2-set avg-pool + final-layer BN during staging + iso rows ----------------
template <int FIRST>
__global__ __launch_bounds__(256) void kgcmm(const float* __restrict__ X,
                                             const float* __restrict__ Wrel,
                                             const float* __restrict__ Wroot,
                                             const float* __restrict__ WrelIso,
                                             const float* __restrict__ WrootIso,
                                             const int* __restrict__ isoIdx,
                                             float* __restrict__ Yrel,
                                             float* __restrict__ Yroot,
                                             const float* __restrict__ pst,
                                             const float* __restrict__ g4,
                                             const float* __restrict__ b4,
                                             const int* __restrict__ a0g,
                                             const float* __restrict__ h2src) {
    __shared__ float sX[64 * 65];
    __shared__ float sR[64 * 64];
    __shared__ float sT[64 * 64];
    __shared__ float sstat[128];
    __shared__ float sSC[64], sSH[64];
    int tid = threadIdx.x, blk = blockIdx.x;
    if (FIRST && tid < 128) {
        float s = 0.f;
        const float* p = pst + tid;
#pragma unroll
        for (int i = 0; i < 32; ++i) s += p[i * 128];
        sstat[tid] = s;
    }
#pragma unroll
    for (int i = tid; i < 1024; i += 256) {
        ((float4*)sR)[i] = ((const float4*)Wrel)[i];
        ((float4*)sT)[i] = ((const float4*)Wroot)[i];
    }
    __syncthreads();
    if (FIRST && tid < 64) {
        float mu = sstat[tid] * (1.f / NN);
        float var = sstat[64 + tid] * (1.f / NN) - mu * mu;
        float sc = g4[tid] * rsqrtf(var + 1e-5f);
        sSC[tid] = sc;
        sSH[tid] = b4[tid] - mu * sc;
    }
    __syncthreads();
#pragma unroll
    for (int i = tid; i < 1024; i += 256) {
        int row = i >> 4, c = (i & 15) << 2;
        float4 v;
        if (FIRST) {
            int grow = blk * 64 + row;
            int na = a0g[2 * grow], nb = a0g[2 * grow + 1];
            float4 va = *(const float4*)(h2src + (size_t)na * 64 + c);
            float4 vb = *(const float4*)(h2src + (size_t)nb * 64 + c);
            v.x = 0.5f * (va.x + vb.x); v.y = 0.5f * (va.y + vb.y);
            v.z = 0.5f * (va.z + vb.z); v.w = 0.5f * (va.w + vb.w);
            v.x = fmaf(v.x, sSC[c], sSH[c]);
            v.y = fmaf(v.y, sSC[c + 1], sSH[c + 1]);
            v.z = fmaf(v.z, sSC[c + 2], sSH[c + 2]);
            v.w = fmaf(v.w, sSC[c + 3], sSH[c + 3]);
        } else {
            v = ((const float4*)(X + (size_t)blk * 4096))[i];
        }
        float* p = sX + row * 65 + c;
        p[0] = v.x; p[1] = v.y; p[2] = v.z; p[3] = v.w;
    }
    __syncthreads();
    int tm = tid >> 4, tn = tid & 15;
    float aR[4][4], aT[4][4];
#pragma unroll
    for (int r = 0; r < 4; ++r)
#pragma unroll
        for (int c = 0; c < 4; ++c) { aR[r][c] = 0.f; aT[r][c] = 0.f; }
    const float* xrow = sX + tm * 4 * 65;
#pragma unroll 4
    for (int k = 0; k < 64; ++k) {
        float a0 = xrow[k], a1 = xrow[65 + k], a2 = xrow[130 + k], a3 = xrow[195 + k];
        float4 br = *(const float4*)(sR + k * 64 + tn * 4);
        float4 bt = *(const float4*)(sT + k * 64 + tn * 4);
        float rb[4] = {br.x, br.y, br.z, br.w};
        float tb[4] = {bt.x, bt.y, bt.z, bt.w};
#pragma unroll
        for (int c = 0; c < 4; ++c) {
            aR[0][c] = fmaf(a0, rb[c], aR[0][c]); aR[1][c] = fmaf(a1, rb[c], aR[1][c]);
            aR[2][c] = fmaf(a2, rb[c], aR[2][c]); aR[3][c] = fmaf(a3, rb[c], aR[3][c]);
            aT[0][c] = fmaf(a0, tb[c], aT[0][c]); aT[1][c] = fmaf(a1, tb[c], aT[1][c]);
            aT[2][c] = fmaf(a2, tb[c], aT[2][c]); aT[3][c] = fmaf(a3, tb[c], aT[3][c]);
        }
    }
#pragma unroll
    for (int r = 0; r < 4; ++r) {
        int row = blk * 64 + tm * 4 + r;
        float4 vr = make_float4(aR[r][0], aR[r][1], aR[r][2], aR[r][3]);
        float4 vt = make_float4(aT[r][0], aT[r][1], aT[r][2], aT[r][3]);
        if (FIRST) {
            int ii = isoIdx[row];
            float4 er = *(const float4*)(WrelIso + (size_t)ii * 64 + tn * 4);
            float4 et = *(const float4*)(WrootIso + (size_t)ii * 64 + tn * 4);
            vr.x += er.x; vr.y += er.y; vr.z += er.z; vr.w += er.w;
            vt.x += et.x; vt.y += et.y; vt.z += et.z; vt.w += et.w;
        }
        *(float4*)(Yrel + (size_t)row * 64 + tn * 4) = vr;
        *(float4*)(Yroot + (size_t)row * 64 + tn * 4) = vt;
    }
}

// ---------------- GraphConv gather: clamped masked chunk-4 (lambda=4) + col prefetch ----------------
__global__ void kgather2(const float* __restrict__ yrel, const float* __restrict__ yroot,
                         const float* __restrict__ brel, const int* __restrict__ offs,
                         const int* __restrict__ col, float* __restrict__ out) {
    int t = blockIdx.x * 256 + threadIdx.x;
    int j = t >> 4, c = t & 15;
    int s0 = offs[j], s1 = offs[j + 1];
    float4 rt = *(const float4*)(yroot + (size_t)j * 64 + 4 * c);
    float4 bb = *(const float4*)(brel + 4 * c);
    float a0 = rt.x + bb.x, a1 = rt.y + bb.y, a2 = rt.z + bb.z, a3 = rt.w + bb.w;
    if (s0 < s1) {
        int vv[4];
#pragma unroll
        for (int jj = 0; jj < 4; ++jj) {
            int idx = s0 + jj; idx = idx < s1 ? idx : s1 - 1;
            vv[jj] = col[idx];
        }
        int e = s0;
        while (true) {
            int ne = e + 4;
            bool more = ne < s1;
            float4 xs[4];
#pragma unroll
            for (int jj = 0; jj < 4; ++jj)
                xs[jj] = *(const float4*)(yrel + (size_t)vv[jj] * 64 + 4 * c);
            int nx[4];
            if (more) {
#pragma unroll
                for (int jj = 0; jj < 4; ++jj) {
                    int idx = ne + jj; idx = idx < s1 ? idx : s1 - 1;
                    nx[jj] = col[idx];
                }
            }
#pragma unroll
            for (int jj = 0; jj < 4; ++jj) {
                float mm = (e + jj < s1) ? 1.f : 0.f;
                a0 = fmaf(xs[jj].x, mm, a0);
                a1 = fmaf(xs[jj].y, mm, a1);
                a2 = fmaf(xs[jj].z, mm, a2);
                a3 = fmaf(xs[jj].w, mm, a3);
            }
            if (!more) break;
            e = ne;
#pragma unroll
            for (int jj = 0; jj < 4; ++jj) vv[jj] = nx[jj];
        }
    }
    *(float4*)(out + (size_t)j * 64 + 4 * c) =
        make_float4(fmaxf(a0, 0.f), fmaxf(a1, 0.f), fmaxf(a2, 0.f), fmaxf(a3, 0.f));
}

// ---------------- per-graph mean pools (x1 gets final BN affine on the mean) ----------------
__global__ void kpoolg(const float* __restrict__ h2, const float* __restrict__ xp2,
                       const float* __restrict__ pst, const float* __restrict__ g4,
                       const float* __restrict__ b4, float* __restrict__ m) {
    __shared__ float sstat[128];
    __shared__ float red[4][64];
    int g = blockIdx.x, tid = threadIdx.x;
    if (tid < 128) {
        float s = 0.f;
        const float* p = pst + tid;
#pragma unroll
        for (int i = 0; i < 32; ++i) s += p[i * 128];
        sstat[tid] = s;
    }
    int wid = tid >> 6, d = tid & 63;
    float s1 = 0.f;
    for (int i = wid; i < 200; i += 4) s1 += h2[((size_t)g * 200 + i) * 64 + d];
    red[wid][d] = s1;
    __syncthreads();
    if (wid == 0) {
        float mean = (red[0][d] + red[1][d] + red[2][d] + red[3][d]) * (1.f / 200.f);
        float mu = sstat[d] * (1.f / NN);
        float var = sstat[64 + d] * (1.f / NN) - mu * mu;
        float sc = g4[d] * rsqrtf(var + 1e-5f);
        m[g * 128 + d] = fmaf(mean, sc, b4[d] - mu * sc);
    }
    __syncthreads();
    float s2 = 0.f;
    for (int i = wid; i < 400; i += 4) s2 += xp2[((size_t)g * 400 + i) * 64 + d];
    red[wid][d] = s2;
    __syncthreads();
    if (wid == 0) m[g * 128 + 64 + d] = (red[0][d] + red[1][d] + red[2][d] + red[3][d]) * (1.f / 400.f);
}

// ---------------- readout MLP ----------------
__global__ void kread(const float* __restrict__ m, const float* __restrict__ W0,
                      const float* __restrict__ b0, const float* __restrict__ W1,
                      const float* __restrict__ b1, const float* __restrict__ W2,
                      const float* __restrict__ b2, const float* __restrict__ lw,
                      const float* __restrict__ lb, float* __restrict__ out) {
    __shared__ float s0[64], s1[32], s2[16];
    int g = blockIdx.x, d = threadIdx.x;
    const float* mr = m + g * 128;
    float t = b0[d];
    for (int k = 0; k < 128; ++k) t = fmaf(mr[k], W0[k * 64 + d], t);
    s0[d] = fmaxf(t, 0.f);
    __syncthreads();
    if (d < 32) {
        float u = b1[d];
        for (int k = 0; k < 64; ++k) u = fmaf(s0[k], W1[k * 32 + d], u);
        s1[d] = fmaxf(u, 0.f);
    }
    __syncthreads();
    if (d < 16) {
        float u = b2[d];
        for (int k = 0; k < 32; ++k) u = fmaf(s1[k], W2[k * 16 + d], u);
        s2[d] = fmaxf(u, 0.f);
    }
    __syncthreads();
    if (d == 0) {
        float u = lb[0];
        for (int k = 0; k < 16; ++k) u = fmaf(s2[k], lw[k], u);
        out[g] = u;
    }
}

// ---------------- host ----------------
extern "C" void kernel_launch(void* const* d_in, const int* in_sizes, int n_in,
                              void* d_out, int out_size, void* d_ws, size_t ws_size,
                              hipStream_t stream) {
    if (ws_size < WS_NEEDED) return;

    const float* x    = (const float*)d_in[0];
    const int*   ei   = (const int*)d_in[1];
    const int*   ea   = (const int*)d_in[2];
    const float* iso  = (const float*)d_in[4];
    const int*   ei2  = (const int*)d_in[5];
    const int*   ai2  = (const int*)d_in[6];
    const float* embW = (const float*)d_in[8];
    const float* embB = (const float*)d_in[9];
    const float* gW1  = (const float*)d_in[10];
    const float* gB1  = (const float*)d_in[11];
    const float* gW2  = (const float*)d_in[12];
    const float* gB2  = (const float*)d_in[13];
    const float* ee1  = (const float*)d_in[14];
    const float* ee2  = (const float*)d_in[15];
    const float* bng  = (const float*)d_in[16];
    const float* bnb  = (const float*)d_in[17];
    const float* i1rW = (const float*)d_in[18];
    const float* i1rB = (const float*)d_in[19];
    const float* i1tW = (const float*)d_in[20];
    const float* i2rW = (const float*)d_in[21];
    const float* i2rB = (const float*)d_in[22];
    const float* i2tW = (const float*)d_in[23];
    const float* roW0 = (const float*)d_in[24];
    const float* roB0 = (const float*)d_in[25];
    const float* roW1 = (const float*)d_in[26];
    const float* roB1 = (const float*)d_in[27];
    const float* roW2 = (const float*)d_in[28];
    const float* roB2 = (const float*)d_in[29];
    const float* lW   = (const float*)d_in[30];
    const float* lB   = (const float*)d_in[31];
    float* out = (float*)d_out;

    char* ws = (char*)d_ws;
    float* h      = (float*)(ws + OFF_H);
    float* hB     = (float*)(ws + OFF_AGG);    // ping-pong buffer B
    float* hA     = (float*)(ws + OFF_H2);     // ping-pong buffer A; final h2
    float* h2     = hA;
    float* xp     = (float*)(ws + OFF_XP);
    float* yrel   = (float*)(ws + OFF_H);      // spans h+hB (both dead post-GIN)
    float* yroot  = (float*)(ws + OFF_YROOT);
    int* offs1    = (int*)(ws + OFF_OFFS1);
    int* col1     = (int*)(ws + OFF_COL1);
    int* offs2    = (int*)(ws + OFF_OFFS2);
    int* col2     = (int*)(ws + OFF_COL2);
    int* isoIdx   = (int*)(ws + OFF_ISO);
    float* mbuf   = (float*)(ws + OFF_M);
    ushort_t* w1h = (ushort_t*)(ws + OFF_YROOT);
    ushort_t* w1l = (ushort_t*)(ws + OFF_YROOT + 81920);
    ushort_t* w2h = (ushort_t*)(ws + OFF_YROOT + 163840);
    ushort_t* w2l = (ushort_t*)(ws + OFF_YROOT + 245760);
    float* pstat2 = (float*)(ws + OFF_CUR1);   // zeroed by memset each launch
    int2* rec1    = (int2*)(ws + OFF_REC1);    // bucketed edge records (xp region; dead before xp writes)
    int2* rec2    = (int2*)(ws + OFF_REC2);
    int* bucketCnt  = (int*)(ws + OFF_CNT1);   // zeroed
    int* bucketBase = (int*)(ws + OFF_BBASE);
    int* perm     = (int*)(ws + OFF_PERM);     // inside xp span; dead before kgather2 writes xp
    int* dbin     = (int*)(ws + OFF_STATS);    // zeroed
    int* dstart   = dbin + 64;
    int* dcur     = dbin + 128;

    const int* src1 = ei;
    const int* dst1 = ei + EE;
    const int* src2 = ei2;
    const int* dst2 = ei2 + EE2;
    const int* a0   = ai2;

    hipMemsetAsync(ws + OFF_CNT1, 0, ZERO_BYTES, stream);

    // bucketed CSR build: LDS ranks + 90K global atomics (replaces 1.23M returning atomics)
    kbA<<<600, 256, 0, stream>>>(src1, dst1, ea, src2, dst2, bucketCnt, rec1, rec2);
    kprepx<<<13240, 256, 0, stream>>>(x, embW, embB, h, gW1, gW2,
                                      w1h, w1l, w2h, w2l, iso, isoIdx);
    kbscan<<<2, 256, 0, stream>>>(bucketCnt, bucketBase);
    kbB<<<300, 256, 0, stream>>>(bucketCnt, bucketBase, rec1, rec2,
                                 offs1, col1, offs2, col2, dbin);
    kdegscan<<<1, 64, 0, stream>>>(dbin, dstart);
    kdegplace<<<NN / 256, 256, 0, stream>>>(offs1, dstart, dcur, perm);

    // GIN layers: fused gather+MLP, h ping-pong (layer 4 lands in hA = h2);
    // ktrans applies BN+ReLU per node between layers (layer-4 output stays raw for the branch)
    for (int l = 0; l < LL; ++l) {
        const float* hin = (l == 0) ? h : ((l & 1) ? hA : hB);
        float* hout = (l & 1) ? hB : hA;
        kglayer<<<NN / 16, 256, 0, stream>>>(
            hin, hout, perm, offs1, col1, ee1 + l * 384, ee2 + l * 192,
            w1h + (size_t)l * 8192, w1l + (size_t)l * 8192,
            w2h + (size_t)l * 8192, w2l + (size_t)l * 8192,
            gB1 + l * 128, gB2 + l * 64,
            pstat2 + (size_t)l * 4096);
        if (l < LL - 1)
            ktrans<<<800, 256, 0, stream>>>(hout, pstat2 + (size_t)l * 4096,
                                            bng + l * 64, bnb + l * 64);
    }

    // 2-set branch (avg-pool + final-layer BN fused into kgcmm<1> staging; kpoolg folds BN on mean)
    kgcmm<1><<<NN2 / 64, 256, 0, stream>>>(xp, i1rW, i1tW, i1rW + 64 * 64,
                                           i1tW + 64 * 64, isoIdx, yrel, yroot,
                                           pstat2 + (size_t)4 * 4096,
                                           bng + 4 * 64, bnb + 4 * 64, a0, h2);
    kgather2<<<NN2 * 16 / 256, 256, 0, stream>>>(yrel, yroot, i1rB, offs2, col2, xp);
    kgcmm<0><<<NN2 / 64, 256, 0, stream>>>(xp, i2rW, i2tW, nullptr, nullptr,
                                           nullptr, yrel, yroot,
                                           nullptr, nullptr, nullptr, nullptr, nullptr);
    kgather2<<<NN2 * 16 / 256, 256, 0, stream>>>(yrel, yroot, i2rB, offs2, col2, xp);

    // pools + readout
    kpoolg<<<GG, 256, 0, stream>>>(h2, xp, pstat2 + (size_t)4 * 4096,
                                   bng + 4 * 64, bnb + 4 * 64, mbuf);
    kread<<<GG, 64, 0, stream>>>(mbuf, roW0, roB0, roW1, roB1, roW2, roB2, lW, lB, out);
}

// Round 7
// 572.144 us; speedup vs baseline: 1.0880x; 1.0338x over previous
//
#include <hip/hip_runtime.h>

#define NN   51200
#define EE   819200
#define GG   256
#define NN2  102400
#define AA   204800
#define EE2  409600
#define DD   64
#define LL   5

// bucket CSR build
#define NB1  100
#define NB2  200
#define CAP1 10240
#define CAP2 3072

typedef __attribute__((ext_vector_type(8))) short bf16x8;
typedef __attribute__((ext_vector_type(4))) float f32x4;
typedef unsigned short ushort_t;

// ---------------- workspace layout (bytes) ----------------
#define OFF_H      ((size_t)0)          // emb h; post-GIN: yrel spans OFF_H..OFF_H2
#define OFF_AGG    ((size_t)13107200)   // GIN: h ping-pong buffer B
#define OFF_H2     ((size_t)26214400)   // GIN: buffer A; layer-4 output = h2 (alive to kpoolg)
#define OFF_XP     ((size_t)39321600)   // rec1/rec2 during CSR build; later xp
#define OFF_REC1   OFF_XP                       // 100*10240*8 = 8,192,000
#define OFF_REC2   ((size_t)47513600)           // 200*3072*8  = 4,915,200 (ends 52,428,800)
#define OFF_PERM   ((size_t)60293120)   // perm (200KB) inside xp region; dead before kgather2 writes xp
#define OFF_YROOT  ((size_t)65536000)   // prepped bf16 weights during GIN; yroot after
#define OFF_OFFS1  ((size_t)91750400)
#define OFF_COL1   ((size_t)91955216)
#define OFF_OFFS2  ((size_t)95232016)
#define OFF_COL2   ((size_t)95641632)
#define OFF_CNT1   ((size_t)97280032)   // zeroed region starts here; bucketCnt[300] lives here
#define OFF_BBASE  ((size_t)97282080)   // bucketBase[300] (inside zeroed region, harmless)
#define OFF_CUR1   ((size_t)97484832)   // pstat2[5][32][128] during GIN (zeroed by memset)
#define OFF_STATS  ((size_t)98508832)   // dbin[64], dstart[64], dcur[64] (zeroed)
#define ZERO_BYTES ((size_t)1231360)
#define OFF_ISO    ((size_t)98511392)
#define OFF_M      ((size_t)98920992)   // graphconv bf16 weight frags (64KB, die before kpoolg); then mbuf
#define WS_NEEDED  ((size_t)99052064)

__device__ __forceinline__ int waveInclScan(int v, int lane) {
#pragma unroll
    for (int off = 1; off < 64; off <<= 1) {
        int t = __shfl_up(v, off, 64);
        if (lane >= off) v += t;
    }
    return v;
}

// ---------------- split-bf16 helpers ----------------
__device__ __forceinline__ void bsplit(float x, ushort_t& hi, ushort_t& lo) {
    union { float f; unsigned u; } a; a.f = x;
    unsigned hb = (a.u + 0x7FFFu + ((a.u >> 16) & 1u)) >> 16;   // RNE to bf16
    union { unsigned u; float f; } h; h.u = hb << 16;
    float r = x - h.f;
    union { float f; unsigned u; } b; b.f = r;
    unsigned lb = (b.u + 0x7FFFu + ((b.u >> 16) & 1u)) >> 16;
    hi = (ushort_t)hb; lo = (ushort_t)lb;
}

// ---------------- bucket build phase A: scatter edges by dst>>9 ----------------
__global__ __launch_bounds__(256) void kbA(const int* __restrict__ src1, const int* __restrict__ dst1,
                                           const int* __restrict__ ea,
                                           const int* __restrict__ src2, const int* __restrict__ dst2,
                                           int* __restrict__ bucketCnt,
                                           int2* __restrict__ rec1, int2* __restrict__ rec2) {
    __shared__ int lhist[256];
    __shared__ int lbase[256];
    int tid = threadIdx.x, b = blockIdx.x;
    lhist[tid] = 0;
    __syncthreads();
    if (b < 400) {
        int i = (b * 256 + tid) * 8;
        int4 d0 = *(const int4*)(dst1 + i);
        int4 d1 = *(const int4*)(dst1 + i + 4);
        int dst[8] = {d0.x, d0.y, d0.z, d0.w, d1.x, d1.y, d1.z, d1.w};
        int bin[8], lr[8];
#pragma unroll
        for (int j = 0; j < 8; ++j) {
            bin[j] = dst[j] >> 9;
            lr[j] = atomicAdd(&lhist[bin[j]], 1);
        }
        __syncthreads();
        if (tid < NB1) {
            int c = lhist[tid];
            lbase[tid] = c ? atomicAdd(&bucketCnt[tid], c) : 0;
        }
        __syncthreads();
        int4 s0 = *(const int4*)(src1 + i);
        int4 s1 = *(const int4*)(src1 + i + 4);
        int src[8] = {s0.x, s0.y, s0.z, s0.w, s1.x, s1.y, s1.z, s1.w};
        int4 e0 = *(const int4*)(ea + 2 * i);
        int4 e1 = *(const int4*)(ea + 2 * i + 4);
        int4 e2 = *(const int4*)(ea + 2 * i + 8);
        int4 e3 = *(const int4*)(ea + 2 * i + 12);
        int code[8] = {e0.x * 3 + e0.y, e0.z * 3 + e0.w, e1.x * 3 + e1.y, e1.z * 3 + e1.w,
                       e2.x * 3 + e2.y, e2.z * 3 + e2.w, e3.x * 3 + e3.y, e3.z * 3 + e3.w};
#pragma unroll
        for (int j = 0; j < 8; ++j) {
            int pos = bin[j] * CAP1 + lbase[bin[j]] + lr[j];
            rec1[pos] = make_int2(src[j] | (code[j] << 16), dst[j]);
        }
    } else {
        int i = ((b - 400) * 256 + tid) * 8;
        int4 d0 = *(const int4*)(dst2 + i);
        int4 d1 = *(const int4*)(dst2 + i + 4);
        int dst[8] = {d0.x, d0.y, d0.z, d0.w, d1.x, d1.y, d1.z, d1.w};
        int bin[8], lr[8];
#pragma unroll
        for (int j = 0; j < 8; ++j) {
            bin[j] = dst[j] >> 9;
            lr[j] = atomicAdd(&lhist[bin[j]], 1);
        }
        __syncthreads();
        if (tid < NB2) {
            int c = lhist[tid];
            lbase[tid] = c ? atomicAdd(&bucketCnt[NB1 + tid], c) : 0;
        }
        __syncthreads();
        int4 s0 = *(const int4*)(src2 + i);
        int4 s1 = *(const int4*)(src2 + i + 4);
        int src[8] = {s0.x, s0.y, s0.z, s0.w, s1.x, s1.y, s1.z, s1.w};
#pragma unroll
        for (int j = 0; j < 8; ++j) {
            int pos = bin[j] * CAP2 + lbase[bin[j]] + lr[j];
            rec2[pos] = make_int2(src[j], dst[j]);
        }
    }
}

// exclusive scan of bucket counts (block 0: g1's 100, block 1: g2's 200)
__global__ void kbscan(const int* __restrict__ bucketCnt, int* __restrict__ bucketBase) {
    __shared__ int wsum[4];
    int tid = threadIdx.x, lane = tid & 63, wid = tid >> 6;
    int nb = blockIdx.x ? NB2 : NB1;
    const int* cnt = bucketCnt + (blockIdx.x ? NB1 : 0);
    int* base = bucketBase + (blockIdx.x ? NB1 : 0);
    int v = (tid < nb) ? cnt[tid] : 0;
    int incl = waveInclScan(v, lane);
    if (lane == 63) wsum[wid] = incl;
    __syncthreads();
    int woff = 0;
#pragma unroll
    for (int w = 0; w < 3; ++w) woff += (w < wid) ? wsum[w] : 0;
    if (tid < nb) base[tid] = woff + incl - v;
}

// ---------------- bucket build phase B: per-bucket CSR (LDS hist + scan + place) ----------------
__global__ __launch_bounds__(256) void kbB(const int* __restrict__ bucketCnt,
                                           const int* __restrict__ bucketBase,
                                           const int2* __restrict__ rec1, const int2* __restrict__ rec2,
                                           int* __restrict__ offs1, int* __restrict__ col1,
                                           int* __restrict__ offs2, int* __restrict__ col2,
                                           int* __restrict__ dbin) {
    __shared__ int nh[512];
    __shared__ int ncur[512];
    __shared__ int wsum[4];
    __shared__ int dhist[64];
    int tid = threadIdx.x, b = blockIdx.x;
    bool g1 = b < NB1;
    const int2* rec = g1 ? (rec1 + (size_t)b * CAP1) : (rec2 + (size_t)(b - NB1) * CAP2);
    int cnt = bucketCnt[b];
    int base = bucketBase[b];
    int* offs = g1 ? offs1 : offs2;
    int* col = g1 ? col1 : col2;
    int nodeBase = g1 ? b * 512 : (b - NB1) * 512;
    nh[tid] = 0; nh[tid + 256] = 0;
    if (tid < 64) dhist[tid] = 0;
    __syncthreads();
    for (int e = tid; e < cnt; e += 256) {
        int2 r = rec[e];
        atomicAdd(&nh[r.y & 511], 1);
    }
    __syncthreads();
    int v0 = nh[2 * tid], v1 = nh[2 * tid + 1];
    int s = v0 + v1;
    int lane = tid & 63, wid = tid >> 6;
    int incl = waveInclScan(s, lane);
    if (lane == 63) wsum[wid] = incl;
    __syncthreads();
    int woff = 0;
#pragma unroll
    for (int w = 0; w < 3; ++w) woff += (w < wid) ? wsum[w] : 0;
    int excl = woff + incl - s;
    ncur[2 * tid] = excl;
    ncur[2 * tid + 1] = excl + v0;
    offs[nodeBase + 2 * tid] = base + excl;
    offs[nodeBase + 2 * tid + 1] = base + excl + v0;
    if (g1) {
        atomicAdd(&dhist[v0 < 63 ? v0 : 63], 1);
        atomicAdd(&dhist[v1 < 63 ? v1 : 63], 1);
    }
    __syncthreads();
    for (int e = tid; e < cnt; e += 256) {
        int2 r = rec[e];
        int node = r.y & 511;
        int slot = base + atomicAdd(&ncur[node], 1);
        col[slot] = r.x;
    }
    if (g1 && tid < 64 && dhist[tid]) atomicAdd(&dbin[tid], dhist[tid]);
    if (tid == 0) {
        if (b == NB1 - 1) offs1[NN] = EE;
        if (b == NB1 + NB2 - 1) offs2[NN2] = EE2;
    }
}

// ---------------- iso argmax: LDS-staged coalesced reads (was strided 144B/lane tail) ----------------
__global__ __launch_bounds__(256) void kiso(const float* __restrict__ iso, int* __restrict__ isoIdx) {
    __shared__ float srow[256 * 36];
    int tid = threadIdx.x;
    int base = blockIdx.x * 256;
    const float4* g4p = (const float4*)(iso + (size_t)base * 36);
#pragma unroll
    for (int i = tid; i < 2304; i += 256) ((float4*)srow)[i] = g4p[i];
    __syncthreads();
    const float* r = srow + tid * 36;
    int best = 0;
#pragma unroll
    for (int k = 0; k < 36; ++k)
        if (r[k] > 0.5f) best = k;
    isoIdx[base + tid] = best;
}

// ---------------- prep: embedding (float4 x loads) + GIN weight prep + GraphConv weight prep ----------------
__global__ void kprepx(const float* __restrict__ x, const float* __restrict__ embW,
                       const float* __restrict__ embB, float* __restrict__ h,
                       const float* __restrict__ gW1, const float* __restrict__ gW2,
                       ushort_t* __restrict__ w1h, ushort_t* __restrict__ w1l,
                       ushort_t* __restrict__ w2h, ushort_t* __restrict__ w2l,
                       const float* __restrict__ i1rW, const float* __restrict__ i1tW,
                       const float* __restrict__ i2rW, const float* __restrict__ i2tW,
                       ushort_t* __restrict__ gcwh, ushort_t* __restrict__ gcwl) {
    int b = blockIdx.x;
    if (b < 12800) {
        int t = b * 256 + threadIdx.x;
        int n = t >> 6, d = t & 63;
        float acc = embB[d];
        const float4* xr4 = (const float4*)(x + (size_t)n * 40);
#pragma unroll
        for (int k4 = 0; k4 < 10; ++k4) {
            float4 xv = xr4[k4];
            acc = fmaf(xv.x, embW[(4 * k4 + 0) * 64 + d], acc);
            acc = fmaf(xv.y, embW[(4 * k4 + 1) * 64 + d], acc);
            acc = fmaf(xv.z, embW[(4 * k4 + 2) * 64 + d], acc);
            acc = fmaf(xv.w, embW[(4 * k4 + 3) * 64 + d], acc);
        }
        h[(size_t)n * 64 + d] = fmaxf(acc, 0.f);
    } else if (b < 12840) {
        int t = (b - 12800) * 256 + threadIdx.x;
        int lane = t & 63, frag = t >> 6;
        int c15 = lane & 15, q = lane >> 4;
        if (frag < 80) {
            int kt = frag & 1, nt = (frag >> 1) & 7, l = frag >> 4;
            const float* W = gW1 + l * 8192;
            ushort_t* oh = w1h + ((size_t)frag * 64 + lane) * 8;
            ushort_t* ol = w1l + ((size_t)frag * 64 + lane) * 8;
            int kb = kt * 32 + q * 8, colw = nt * 16 + c15;
#pragma unroll
            for (int j = 0; j < 8; ++j) {
                ushort_t hi, lo; bsplit(W[(kb + j) * 128 + colw], hi, lo);
                oh[j] = hi; ol[j] = lo;
            }
        } else if (frag < 160) {
            int f = frag - 80;
            int kt = f & 3, nt = (f >> 2) & 3, l = f >> 4;
            const float* W = gW2 + l * 8192;
            ushort_t* oh = w2h + ((size_t)f * 64 + lane) * 8;
            ushort_t* ol = w2l + ((size_t)f * 64 + lane) * 8;
            int kb = kt * 32 + q * 8, colw = nt * 16 + c15;
#pragma unroll
            for (int j = 0; j < 8; ++j) {
                ushort_t hi, lo; bsplit(W[(kb + j) * 64 + colw], hi, lo);
                oh[j] = hi; ol[j] = lo;
            }
        }
    } else {
        // GraphConv weight prep: 4 matrices x 8 frags (K=64, N=64), same fragment packing as GIN
        int t = (b - 12840) * 256 + threadIdx.x;   // 0..2047
        int lane = t & 63, frag = t >> 6;          // frag 0..31
        int c15 = lane & 15, q = lane >> 4;
        int m = frag >> 3, f = frag & 7;
        int kt = f & 1, nt = f >> 1;
        const float* W = (m == 0) ? i1rW : (m == 1) ? i1tW : (m == 2) ? i2rW : i2tW;
        ushort_t* oh = gcwh + (size_t)m * 4096 + ((size_t)f * 64 + lane) * 8;
        ushort_t* ol = gcwl + (size_t)m * 4096 + ((size_t)f * 64 + lane) * 8;
        int kb = kt * 32 + q * 8, colw = nt * 16 + c15;
#pragma unroll
        for (int j = 0; j < 8; ++j) {
            ushort_t hi, lo; bsplit(W[(kb + j) * 64 + colw], hi, lo);
            oh[j] = hi; ol[j] = lo;
        }
    }
}

// ASCENDING placement (R3/R4 behavior — measured faster than descending)
__global__ void kdegscan(const int* __restrict__ dbin, int* __restrict__ dstart) {
    int tid = threadIdx.x;
    int v = dbin[tid];
    int incl = waveInclScan(v, tid);
    dstart[tid] = incl - v;
}

// two-level counting-sort placement: LDS-local ranks + one global atomic per (block,bin)
__global__ __launch_bounds__(256) void kdegplace(const int* __restrict__ offs,
                                                 const int* __restrict__ dstart,
                                                 int* __restrict__ dcur,
                                                 int* __restrict__ perm) {
    __shared__ int lhist[64];
    __shared__ int lbase[64];
    int tid = threadIdx.x;
    if (tid < 64) lhist[tid] = 0;
    __syncthreads();
    int n = blockIdx.x * 256 + tid;
    int d = offs[n + 1] - offs[n]; d = d < 63 ? d : 63;
    int lr = atomicAdd(&lhist[d], 1);
    __syncthreads();
    if (tid < 64) {
        int c = lhist[tid];
        lbase[tid] = c ? atomicAdd(&dcur[tid], c) : 0;
    }
    __syncthreads();
    perm[dstart[d] + lbase[d] + lr] = n;
}

// ---------------- per-node BN+ReLU transform, in place (once per node, not per edge) ----------------
__global__ __launch_bounds__(256) void ktrans(float* __restrict__ h,
                                              const float* __restrict__ pst,
                                              const float* __restrict__ gamma,
                                              const float* __restrict__ beta) {
    __shared__ float sstat[128];
    __shared__ float sSC[64], sSH[64];
    int tid = threadIdx.x;
    if (tid < 128) {
        float s = 0.f;
        const float* p = pst + tid;
#pragma unroll
        for (int i = 0; i < 32; ++i) s += p[i * 128];
        sstat[tid] = s;
    }
    __syncthreads();
    if (tid < 64) {
        float mu = sstat[tid] * (1.f / NN);
        float var = sstat[64 + tid] * (1.f / NN) - mu * mu;
        float sc = gamma[tid] * rsqrtf(var + 1e-5f);
        sSC[tid] = sc; sSH[tid] = beta[tid] - mu * sc;
    }
    __syncthreads();
    int c = (tid & 15) * 4;
    float4 sc4 = *(const float4*)(sSC + c);
    float4 sh4 = *(const float4*)(sSH + c);
    float4* hp = (float4*)h;
    size_t base = (size_t)blockIdx.x * 1024 + tid;
#pragma unroll
    for (int r = 0; r < 4; ++r) {
        float4 v = hp[base + r * 256];
        v.x = fmaxf(fmaf(v.x, sc4.x, sh4.x), 0.f);
        v.y = fmaxf(fmaf(v.y, sc4.y, sh4.y), 0.f);
        v.z = fmaxf(fmaf(v.z, sc4.z, sh4.z), 0.f);
        v.w = fmaxf(fmaf(v.w, sc4.w, sh4.w), 0.f);
        hp[base + r * 256] = v;
    }
}

// ---------------- fused GIN layer: gather(16 perm'd nodes) -> LDS -> MFMA MLP -> hout + stats ----
__global__ __launch_bounds__(256) void kglayer(
    const float* __restrict__ hin, float* __restrict__ hout,
    const int* __restrict__ perm,
    const int* __restrict__ offs, const int* __restrict__ col,
    const float* __restrict__ e1, const float* __restrict__ e2,
    const ushort_t* __restrict__ w1h, const ushort_t* __restrict__ w1l,
    const ushort_t* __restrict__ w2h, const ushort_t* __restrict__ w2l,
    const float* __restrict__ b1, const float* __restrict__ b2,
    float* __restrict__ pstout) {
    __shared__ float etab[13 * 64];
    __shared__ int sPerm[16];
    __shared__ float sMLP[16 * 132];   // sA stride-68 aliases front; sH stride-132
    float* sA = sMLP;
    float* sH = sMLP;
    int tid = threadIdx.x;
    if (tid < 16) sPerm[tid] = perm[blockIdx.x * 16 + tid];
    for (int idx = tid; idx < 13 * 64; idx += 256) {
        int ci = idx >> 6, dd = idx & 63;
        etab[idx] = e1[(ci / 3) * 64 + dd] + e2[(ci % 3) * 64 + dd];
    }
    __syncthreads();
    int lane = tid & 63, wv = tid >> 6;
    int c15 = lane & 15, q = lane >> 4;

    // ---- gather node n into sA ----
    {
        int n = sPerm[wv * 4 + q];
        int s0 = offs[n], s1 = offs[n + 1];
        float4 sx = *(const float4*)(hin + (size_t)n * 64 + 4 * c15);
        float4 et = *(const float4*)(etab + 12 * 64 + 4 * c15);
        float a0 = sx.x + et.x, a1 = sx.y + et.y, a2 = sx.z + et.z, a3 = sx.w + et.w;
        int deg = s1 - s0;
        if (deg > 0) {
            const int* cp = col + s0;
            int nfull = deg >> 3, rem = deg & 7;
            int vv[8];
#pragma unroll
            for (int j = 0; j < 8; ++j) {
                int idx = j < deg ? j : deg - 1;
                vv[j] = cp[idx];
            }
            for (int it = 0; it < nfull; ++it) {
                float4 xv[8], tv[8];
#pragma unroll
                for (int j = 0; j < 8; ++j) {
                    xv[j] = *(const float4*)(hin + (size_t)(vv[j] & 0xFFFF) * 64 + 4 * c15);
                    tv[j] = *(const float4*)(etab + (vv[j] >> 16) * 64 + 4 * c15);
                }
                int e8 = (it + 1) * 8;
                bool more = e8 < deg;
                int nx[8];
                if (more) {
#pragma unroll
                    for (int j = 0; j < 8; ++j) {
                        int idx = e8 + j; idx = idx < deg ? idx : deg - 1;
                        nx[j] = cp[idx];
                    }
                }
#pragma unroll
                for (int j = 0; j < 8; ++j) {
                    a0 += xv[j].x + tv[j].x;
                    a1 += xv[j].y + tv[j].y;
                    a2 += xv[j].z + tv[j].z;
                    a3 += xv[j].w + tv[j].w;
                }
                if (more) {
#pragma unroll
                    for (int j = 0; j < 8; ++j) vv[j] = nx[j];
                }
            }
            if (rem) {
                float4 xv[8], tv[8];
#pragma unroll
                for (int j = 0; j < 8; ++j) {
                    xv[j] = *(const float4*)(hin + (size_t)(vv[j] & 0xFFFF) * 64 + 4 * c15);
                    tv[j] = *(const float4*)(etab + (vv[j] >> 16) * 64 + 4 * c15);
                }
#pragma unroll
                for (int j = 0; j < 8; ++j) {
                    float mm = (j < rem) ? 1.f : 0.f;
                    a0 = fmaf(xv[j].x + tv[j].x, mm, a0);
                    a1 = fmaf(xv[j].y + tv[j].y, mm, a1);
                    a2 = fmaf(xv[j].z + tv[j].z, mm, a2);
                    a3 = fmaf(xv[j].w + tv[j].w, mm, a3);
                }
            }
        }
        *(float4*)(sA + (wv * 4 + q) * 68 + 4 * c15) = make_float4(a0, a1, a2, a3);
    }
    __syncthreads();

    // ---- A-frags to regs (sA dies after next sync; sH aliases) ----
    bf16x8 ah[2], al[2];
#pragma unroll
    for (int kt = 0; kt < 2; ++kt) {
        const float* p = sA + c15 * 68 + kt * 32 + q * 8;
        float4 x0 = *(const float4*)p;
        float4 x1 = *(const float4*)(p + 4);
        float xs[8] = {x0.x, x0.y, x0.z, x0.w, x1.x, x1.y, x1.z, x1.w};
#pragma unroll
        for (int j = 0; j < 8; ++j) {
            ushort_t hi, lo; bsplit(xs[j], hi, lo);
            ah[kt][j] = (short)hi; al[kt][j] = (short)lo;
        }
    }
    __syncthreads();

    // ---- GEMM1: nt = 2wv+j ----
    f32x4 acc1[2];
#pragma unroll
    for (int j = 0; j < 2; ++j) { f32x4 z = {0.f, 0.f, 0.f, 0.f}; acc1[j] = z; }
#pragma unroll
    for (int kt = 0; kt < 2; ++kt) {
#pragma unroll
        for (int j = 0; j < 2; ++j) {
            int nt = 2 * wv + j;
            size_t fo = ((size_t)((nt * 2 + kt) * 64 + lane)) * 8;
            bf16x8 bh = *(const bf16x8*)(w1h + fo);
            bf16x8 bl = *(const bf16x8*)(w1l + fo);
            acc1[j] = __builtin_amdgcn_mfma_f32_16x16x32_bf16(ah[kt], bh, acc1[j], 0, 0, 0);
            acc1[j] = __builtin_amdgcn_mfma_f32_16x16x32_bf16(al[kt], bh, acc1[j], 0, 0, 0);
            acc1[j] = __builtin_amdgcn_mfma_f32_16x16x32_bf16(ah[kt], bl, acc1[j], 0, 0, 0);
        }
    }
#pragma unroll
    for (int j = 0; j < 2; ++j) {
        int nt = 2 * wv + j;
        float bias = b1[nt * 16 + c15];
#pragma unroll
        for (int rg = 0; rg < 4; ++rg)
            sH[(4 * q + rg) * 132 + nt * 16 + c15] = fmaxf(acc1[j][rg] + bias, 0.f);
    }
    __syncthreads();

    // ---- GEMM2: nt = wv ----
    f32x4 acc2 = {0.f, 0.f, 0.f, 0.f};
#pragma unroll
    for (int kt = 0; kt < 4; ++kt) {
        const float* p = sH + c15 * 132 + kt * 32 + q * 8;
        float4 x0 = *(const float4*)p;
        float4 x1 = *(const float4*)(p + 4);
        float xs[8] = {x0.x, x0.y, x0.z, x0.w, x1.x, x1.y, x1.z, x1.w};
        bf16x8 a2h, a2l;
#pragma unroll
        for (int j = 0; j < 8; ++j) {
            ushort_t hi, lo; bsplit(xs[j], hi, lo);
            a2h[j] = (short)hi; a2l[j] = (short)lo;
        }
        size_t fo = ((size_t)((wv * 4 + kt) * 64 + lane)) * 8;
        bf16x8 bh = *(const bf16x8*)(w2h + fo);
        bf16x8 bl = *(const bf16x8*)(w2l + fo);
        acc2 = __builtin_amdgcn_mfma_f32_16x16x32_bf16(a2h, bh, acc2, 0, 0, 0);
        acc2 = __builtin_amdgcn_mfma_f32_16x16x32_bf16(a2l, bh, acc2, 0, 0, 0);
        acc2 = __builtin_amdgcn_mfma_f32_16x16x32_bf16(a2h, bl, acc2, 0, 0, 0);
    }
    {
        float bias = b2[wv * 16 + c15];
        float s = 0.f, s2 = 0.f;
#pragma unroll
        for (int rg = 0; rg < 4; ++rg) {
            float v = acc2[rg] + bias;
            hout[(size_t)sPerm[4 * q + rg] * 64 + wv * 16 + c15] = v;
            s += v; s2 += v * v;
        }
        s += __shfl_xor(s, 16, 64);  s += __shfl_xor(s, 32, 64);
        s2 += __shfl_xor(s2, 16, 64); s2 += __shfl_xor(s2, 32, 64);
        if (q == 0) {
            float* ps = pstout + (size_t)(blockIdx.x & 31) * 128;
            atomicAdd(&ps[wv * 16 + c15], s);
            atomicAdd(&ps[64 + wv * 16 + c15], s2);
        }
    }
}

// ---------------- GraphConv GEMMs via split-bf16 MFMA ----------------
// X[64,64] @ {Wrel, Wroot} per block; weights come as prepped bf16 hi/lo fragment tables (L2-hot).
// FIRST fuses 2-set avg-pool + final-layer BN during staging; iso rows added in epilogue.
template <int FIRST>
__global__ __launch_bounds__(256) void kgcmm(const float* __restrict__ X,
                                             const ushort_t* __restrict__ grh,
                                             const ushort_t* __restrict__ grl,
                                             const ushort_t* __restrict__ gth,
                                             const ushort_t* __restrict__ gtl,
                                             const float* __restrict__ WrelIso,
                                             const float* __restrict__ WrootIso,
                                             const int* __restrict__ isoIdx,
                                             float* __restrict__ Yrel,
                                             float* __restrict__ Yroot,
                                             const float* __restrict__ pst,
                                             const float* __restrict__ g4,
                                             const float* __restrict__ b4,
                                             const int* __restrict__ a0g,
                                             const float* __restrict__ h2src) {
    __shared__ float sX[64 * 68];
    __shared__ float sstat[128];
    __shared__ float sSC[64], sSH[64];
    int tid = threadIdx.x, blk = blockIdx.x;
    if (FIRST && tid < 128) {
        float s = 0.f;
        const float* p = pst + tid;
#pragma unroll
        for (int i = 0; i < 32; ++i) s += p[i * 128];
        sstat[tid] = s;
    }
    __syncthreads();
    if (FIRST && tid < 64) {
        float mu = sstat[tid] * (1.f / NN);
        float var = sstat[64 + tid] * (1.f / NN) - mu * mu;
        float sc = g4[tid] * rsqrtf(var + 1e-5f);
        sSC[tid] = sc;
        sSH[tid] = b4[tid] - mu * sc;
    }
    __syncthreads();
#pragma unroll
    for (int i = tid; i < 1024; i += 256) {
        int row = i >> 4, c = (i & 15) << 2;
        float4 v;
        if (FIRST) {
            int grow = blk * 64 + row;
            int na = a0g[2 * grow], nb = a0g[2 * grow + 1];
            float4 va = *(const float4*)(h2src + (size_t)na * 64 + c);
            float4 vb = *(const float4*)(h2src + (size_t)nb * 64 + c);
            v.x = 0.5f * (va.x + vb.x); v.y = 0.5f * (va.y + vb.y);
            v.z = 0.5f * (va.z + vb.z); v.w = 0.5f * (va.w + vb.w);
            v.x = fmaf(v.x, sSC[c], sSH[c]);
            v.y = fmaf(v.y, sSC[c + 1], sSH[c + 1]);
            v.z = fmaf(v.z, sSC[c + 2], sSH[c + 2]);
            v.w = fmaf(v.w, sSC[c + 3], sSH[c + 3]);
        } else {
            v = ((const float4*)(X + (size_t)blk * 4096))[i];
        }
        float* p = sX + row * 68 + c;
        p[0] = v.x; p[1] = v.y; p[2] = v.z; p[3] = v.w;
    }
    __syncthreads();
    int lane = tid & 63, wv = tid >> 6;
    int c15 = lane & 15, q = lane >> 4;

    // A-frags: wave wv owns output rows 16wv..16wv+15
    bf16x8 ah[2], al[2];
#pragma unroll
    for (int kt = 0; kt < 2; ++kt) {
        const float* p = sX + (16 * wv + c15) * 68 + kt * 32 + q * 8;
        float4 x0 = *(const float4*)p;
        float4 x1 = *(const float4*)(p + 4);
        float xs[8] = {x0.x, x0.y, x0.z, x0.w, x1.x, x1.y, x1.z, x1.w};
#pragma unroll
        for (int j = 0; j < 8; ++j) {
            ushort_t hi, lo; bsplit(xs[j], hi, lo);
            ah[kt][j] = (short)hi; al[kt][j] = (short)lo;
        }
    }

    f32x4 accR[4], accT[4];
#pragma unroll
    for (int nt = 0; nt < 4; ++nt) {
        f32x4 z = {0.f, 0.f, 0.f, 0.f};
        accR[nt] = z; accT[nt] = z;
    }
#pragma unroll
    for (int nt = 0; nt < 4; ++nt) {
#pragma unroll
        for (int kt = 0; kt < 2; ++kt) {
            size_t fo = ((size_t)((nt * 2 + kt) * 64 + lane)) * 8;
            bf16x8 bh = *(const bf16x8*)(grh + fo);
            bf16x8 bl = *(const bf16x8*)(grl + fo);
            accR[nt] = __builtin_amdgcn_mfma_f32_16x16x32_bf16(ah[kt], bh, accR[nt], 0, 0, 0);
            accR[nt] = __builtin_amdgcn_mfma_f32_16x16x32_bf16(al[kt], bh, accR[nt], 0, 0, 0);
            accR[nt] = __builtin_amdgcn_mfma_f32_16x16x32_bf16(ah[kt], bl, accR[nt], 0, 0, 0);
            bf16x8 ch = *(const bf16x8*)(gth + fo);
            bf16x8 cl = *(const bf16x8*)(gtl + fo);
            accT[nt] = __builtin_amdgcn_mfma_f32_16x16x32_bf16(ah[kt], ch, accT[nt], 0, 0, 0);
            accT[nt] = __builtin_amdgcn_mfma_f32_16x16x32_bf16(al[kt], ch, accT[nt], 0, 0, 0);
            accT[nt] = __builtin_amdgcn_mfma_f32_16x16x32_bf16(ah[kt], cl, accT[nt], 0, 0, 0);
        }
    }

    // epilogue: row = blk*64 + 16wv + 4q + rg, col = nt*16 + c15
    int rbase = blk * 64 + 16 * wv + 4 * q;
#pragma unroll
    for (int rg = 0; rg < 4; ++rg) {
        int row = rbase + rg;
        int ii = FIRST ? isoIdx[row] : 0;
        float* yr = Yrel + (size_t)row * 64;
        float* yt = Yroot + (size_t)row * 64;
        const float* er = WrelIso + (size_t)ii * 64;
        const float* et = WrootIso + (size_t)ii * 64;
#pragma unroll
        for (int nt = 0; nt < 4; ++nt) {
            int cc = nt * 16 + c15;
            float vr = accR[nt][rg], vt = accT[nt][rg];
            if (FIRST) { vr += er[cc]; vt += et[cc]; }
            yr[cc] = vr;
            yt[cc] = vt;
        }
    }
}

// ---------------- GraphConv gather: clamped masked chunk-4 (lambda=4) + col prefetch ----------------
__global__ void kgather2(const float* __restrict__ yrel, const float* __restrict__ yroot,
                         const float* __restrict__ brel, const int* __restrict__ offs,
                         const int* __restrict__ col, float* __restrict__ out) {
    int t = blockIdx.x * 256 + threadIdx.x;
    int j = t >> 4, c = t & 15;
    int s0 = offs[j], s1 = offs[j + 1];
    float4 rt = *(const float4*)(yroot + (size_t)j * 64 + 4 * c);
    float4 bb = *(const float4*)(brel + 4 * c);
    float a0 = rt.x + bb.x, a1 = rt.y + bb.y, a2 = rt.z + bb.z, a3 = rt.w + bb.w;
    if (s0 < s1) {
        int vv[4];
#pragma unroll
        for (int jj = 0; jj < 4; ++jj) {
            int idx = s0 + jj; idx = idx < s1 ? idx : s1 - 1;
            vv[jj] = col[idx];
        }
        int e = s0;
        while (true) {
            int ne = e + 4;
            bool more = ne < s1;
            float4 xs[4];
#pragma unroll
            for (int jj = 0; jj < 4; ++jj)
                xs[jj] = *(const float4*)(yrel + (size_t)vv[jj] * 64 + 4 * c);
            int nx[4];
            if (more) {
#pragma unroll
                for (int jj = 0; jj < 4; ++jj) {
                    int idx = ne + jj; idx = idx < s1 ? idx : s1 - 1;
                    nx[jj] = col[idx];
                }
            }
#pragma unroll
            for (int jj = 0; jj < 4; ++jj) {
                float mm = (e + jj < s1) ? 1.f : 0.f;
                a0 = fmaf(xs[jj].x, mm, a0);
                a1 = fmaf(xs[jj].y, mm, a1);
                a2 = fmaf(xs[jj].z, mm, a2);
                a3 = fmaf(xs[jj].w, mm, a3);
            }
            if (!more) break;
            e = ne;
#pragma unroll
            for (int jj = 0; jj < 4; ++jj) vv[jj] = nx[jj];
        }
    }
    *(float4*)(out + (size_t)j * 64 + 4 * c) =
        make_float4(fmaxf(a0, 0.f), fmaxf(a1, 0.f), fmaxf(a2, 0.f), fmaxf(a3, 0.f));
}

// ---------------- per-graph mean pools (x1 gets final BN affine on the mean) ----------------
__global__ void kpoolg(const float* __restrict__ h2, const float* __restrict__ xp2,
                       const float* __restrict__ pst, const float* __restrict__ g4,
                       const float* __restrict__ b4, float* __restrict__ m) {
    __shared__ float sstat[128];
    __shared__ float red[4][64];
    int g = blockIdx.x, tid = threadIdx.x;
    if (tid < 128) {
        float s = 0.f;
        const float* p = pst + tid;
#pragma unroll
        for (int i = 0; i < 32; ++i) s += p[i * 128];
        sstat[tid] = s;
    }
    int wid = tid >> 6, d = tid & 63;
    float s1 = 0.f;
    for (int i = wid; i < 200; i += 4) s1 += h2[((size_t)g * 200 + i) * 64 + d];
    red[wid][d] = s1;
    __syncthreads();
    if (wid == 0) {
        float mean = (red[0][d] + red[1][d] + red[2][d] + red[3][d]) * (1.f / 200.f);
        float mu = sstat[d] * (1.f / NN);
        float var = sstat[64 + d] * (1.f / NN) - mu * mu;
        float sc = g4[d] * rsqrtf(var + 1e-5f);
        m[g * 128 + d] = fmaf(mean, sc, b4[d] - mu * sc);
    }
    __syncthreads();
    float s2 = 0.f;
    for (int i = wid; i < 400; i += 4) s2 += xp2[((size_t)g * 400 + i) * 64 + d];
    red[wid][d] = s2;
    __syncthreads();
    if (wid == 0) m[g * 128 + 64 + d] = (red[0][d] + red[1][d] + red[2][d] + red[3][d]) * (1.f / 400.f);
}

// ---------------- readout MLP ----------------
__global__ void kread(const float* __restrict__ m, const float* __restrict__ W0,
                      const float* __restrict__ b0, const float* __restrict__ W1,
                      const float* __restrict__ b1, const float* __restrict__ W2,
                      const float* __restrict__ b2, const float* __restrict__ lw,
                      const float* __restrict__ lb, float* __restrict__ out) {
    __shared__ float s0[64], s1[32], s2[16];
    int g = blockIdx.x, d = threadIdx.x;
    const float* mr = m + g * 128;
    float t = b0[d];
    for (int k = 0; k < 128; ++k) t = fmaf(mr[k], W0[k * 64 + d], t);
    s0[d] = fmaxf(t, 0.f);
    __syncthreads();
    if (d < 32) {
        float u = b1[d];
        for (int k = 0; k < 64; ++k) u = fmaf(s0[k], W1[k * 32 + d], u);
        s1[d] = fmaxf(u, 0.f);
    }
    __syncthreads();
    if (d < 16) {
        float u = b2[d];
        for (int k = 0; k < 32; ++k) u = fmaf(s1[k], W2[k * 16 + d], u);
        s2[d] = fmaxf(u, 0.f);
    }
    __syncthreads();
    if (d == 0) {
        float u = lb[0];
        for (int k = 0; k < 16; ++k) u = fmaf(s2[k], lw[k], u);
        out[g] = u;
    }
}

// ---------------- host ----------------
extern "C" void kernel_launch(void* const* d_in, const int* in_sizes, int n_in,
                              void* d_out, int out_size, void* d_ws, size_t ws_size,
                              hipStream_t stream) {
    if (ws_size < WS_NEEDED) return;

    const float* x    = (const float*)d_in[0];
    const int*   ei   = (const int*)d_in[1];
    const int*   ea   = (const int*)d_in[2];
    const float* iso  = (const float*)d_in[4];
    const int*   ei2  = (const int*)d_in[5];
    const int*   ai2  = (const int*)d_in[6];
    const float* embW = (const float*)d_in[8];
    const float* embB = (const float*)d_in[9];
    const float* gW1  = (const float*)d_in[10];
    const float* gB1  = (const float*)d_in[11];
    const float* gW2  = (const float*)d_in[12];
    const float* gB2  = (const float*)d_in[13];
    const float* ee1  = (const float*)d_in[14];
    const float* ee2  = (const float*)d_in[15];
    const float* bng  = (const float*)d_in[16];
    const float* bnb  = (const float*)d_in[17];
    const float* i1rW = (const float*)d_in[18];
    const float* i1rB = (const float*)d_in[19];
    const float* i1tW = (const float*)d_in[20];
    const float* i2rW = (const float*)d_in[21];
    const float* i2rB = (const float*)d_in[22];
    const float* i2tW = (const float*)d_in[23];
    const float* roW0 = (const float*)d_in[24];
    const float* roB0 = (const float*)d_in[25];
    const float* roW1 = (const float*)d_in[26];
    const float* roB1 = (const float*)d_in[27];
    const float* roW2 = (const float*)d_in[28];
    const float* roB2 = (const float*)d_in[29];
    const float* lW   = (const float*)d_in[30];
    const float* lB   = (const float*)d_in[31];
    float* out = (float*)d_out;

    char* ws = (char*)d_ws;
    float* h      = (float*)(ws + OFF_H);
    float* hB     = (float*)(ws + OFF_AGG);    // ping-pong buffer B
    float* hA     = (float*)(ws + OFF_H2);     // ping-pong buffer A; final h2
    float* h2     = hA;
    float* xp     = (float*)(ws + OFF_XP);
    float* yrel   = (float*)(ws + OFF_H);      // spans h+hB (both dead post-GIN)
    float* yroot  = (float*)(ws + OFF_YROOT);
    int* offs1    = (int*)(ws + OFF_OFFS1);
    int* col1     = (int*)(ws + OFF_COL1);
    int* offs2    = (int*)(ws + OFF_OFFS2);
    int* col2     = (int*)(ws + OFF_COL2);
    int* isoIdx   = (int*)(ws + OFF_ISO);
    float* mbuf   = (float*)(ws + OFF_M);      // written by kpoolg AFTER gcw frags die
    ushort_t* w1h = (ushort_t*)(ws + OFF_YROOT);
    ushort_t* w1l = (ushort_t*)(ws + OFF_YROOT + 81920);
    ushort_t* w2h = (ushort_t*)(ws + OFF_YROOT + 163840);
    ushort_t* w2l = (ushort_t*)(ws + OFF_YROOT + 245760);
    ushort_t* gcwh = (ushort_t*)(ws + OFF_M);           // 4 matrices x 4096 ushorts
    ushort_t* gcwl = (ushort_t*)(ws + OFF_M + 32768);
    float* pstat2 = (float*)(ws + OFF_CUR1);   // zeroed by memset each launch
    int2* rec1    = (int2*)(ws + OFF_REC1);    // bucketed edge records (xp region; dead before xp writes)
    int2* rec2    = (int2*)(ws + OFF_REC2);
    int* bucketCnt  = (int*)(ws + OFF_CNT1);   // zeroed
    int* bucketBase = (int*)(ws + OFF_BBASE);
    int* perm     = (int*)(ws + OFF_PERM);     // inside xp span; dead before kgather2 writes xp
    int* dbin     = (int*)(ws + OFF_STATS);    // zeroed
    int* dstart   = dbin + 64;
    int* dcur     = dbin + 128;

    const int* src1 = ei;
    const int* dst1 = ei + EE;
    const int* src2 = ei2;
    const int* dst2 = ei2 + EE2;
    const int* a0   = ai2;

    hipMemsetAsync(ws + OFF_CNT1, 0, ZERO_BYTES, stream);

    // bucketed CSR build: LDS ranks + 90K global atomics (replaces 1.23M returning atomics)
    kbA<<<600, 256, 0, stream>>>(src1, dst1, ea, src2, dst2, bucketCnt, rec1, rec2);
    kiso<<<NN2 / 256, 256, 0, stream>>>(iso, isoIdx);
    kprepx<<<12848, 256, 0, stream>>>(x, embW, embB, h, gW1, gW2,
                                      w1h, w1l, w2h, w2l,
                                      i1rW, i1tW, i2rW, i2tW, gcwh, gcwl);
    kbscan<<<2, 256, 0, stream>>>(bucketCnt, bucketBase);
    kbB<<<300, 256, 0, stream>>>(bucketCnt, bucketBase, rec1, rec2,
                                 offs1, col1, offs2, col2, dbin);
    kdegscan<<<1, 64, 0, stream>>>(dbin, dstart);
    kdegplace<<<NN / 256, 256, 0, stream>>>(offs1, dstart, dcur, perm);

    // GIN layers: fused gather+MLP, h ping-pong (layer 4 lands in hA = h2);
    // ktrans applies BN+ReLU per node between layers (layer-4 output stays raw for the branch)
    for (int l = 0; l < LL; ++l) {
        const float* hin = (l == 0) ? h : ((l & 1) ? hA : hB);
        float* hout = (l & 1) ? hB : hA;
        kglayer<<<NN / 16, 256, 0, stream>>>(
            hin, hout, perm, offs1, col1, ee1 + l * 384, ee2 + l * 192,
            w1h + (size_t)l * 8192, w1l + (size_t)l * 8192,
            w2h + (size_t)l * 8192, w2l + (size_t)l * 8192,
            gB1 + l * 128, gB2 + l * 64,
            pstat2 + (size_t)l * 4096);
        if (l < LL - 1)
            ktrans<<<800, 256, 0, stream>>>(hout, pstat2 + (size_t)l * 4096,
                                            bng + l * 64, bnb + l * 64);
    }

    // 2-set branch (avg-pool + final-layer BN fused into kgcmm<1> staging; MFMA GEMMs)
    kgcmm<1><<<NN2 / 64, 256, 0, stream>>>(xp,
                                           gcwh, gcwl, gcwh + 4096, gcwl + 4096,
                                           i1rW + 64 * 64, i1tW + 64 * 64, isoIdx,
                                           yrel, yroot,
                                           pstat2 + (size_t)4 * 4096,
                                           bng + 4 * 64, bnb + 4 * 64, a0, h2);
    kgather2<<<NN2 * 16 / 256, 256, 0, stream>>>(yrel, yroot, i1rB, offs2, col2, xp);
    kgcmm<0><<<NN2 / 64, 256, 0, stream>>>(xp,
                                           gcwh + 8192, gcwl + 8192, gcwh + 12288, gcwl + 12288,
                                           nullptr, nullptr, nullptr,
                                           yrel, yroot,
                                           nullptr, nullptr, nullptr, nullptr, nullptr);
    kgather2<<<NN2 * 16 / 256, 256, 0, stream>>>(yrel, yroot, i2rB, offs2, col2, xp);

    // pools + readout
    kpoolg<<<GG, 256, 0, stream>>>(h2, xp, pstat2 + (size_t)4 * 4096,
                                   bng + 4 * 64, bnb + 4 * 64, mbuf);
    kread<<<GG, 64, 0, stream>>>(mbuf, roW0, roB0, roW1, roB1, roW2, roB2, lW, lB, out);
}